// Round 10
// baseline (848.384 us; speedup 1.0000x reference)
//
#include <hip/hip_runtime.h>
#include <hip/hip_bf16.h>

#define HH 128
#define WW 128
#define NPIX 16384

using bf16 = __hip_bfloat16;
typedef __attribute__((ext_vector_type(8))) short short8;
typedef __attribute__((ext_vector_type(4))) float f32x4;

__device__ __forceinline__ float b2f(bf16 x){ return __bfloat162float(x); }
__device__ __forceinline__ bf16 f2b(float x){ return __float2bfloat16(x); }
__device__ __forceinline__ unsigned short f2bu(float x){
  bf16 h = __float2bfloat16(x);
  return __builtin_bit_cast(unsigned short, h);
}
__device__ __forceinline__ unsigned short bbits(bf16 x){
  return __builtin_bit_cast(unsigned short, x);
}
__device__ __forceinline__ float u16f(unsigned short u){
  return __bfloat162float(__builtin_bit_cast(bf16, u));
}
__device__ __forceinline__ void bf2x(unsigned int u, float& a, float& b){
  a = u16f((unsigned short)(u & 0xffffu));
  b = u16f((unsigned short)(u >> 16));
}
__device__ __forceinline__ unsigned int relu2(unsigned int x){
  unsigned int s = x & 0x80008000u;
  unsigned int t = s >> 15;
  unsigned int m = (t << 16) - t;
  return x & ~m;
}
__device__ __forceinline__ float hswish(float x){
  float t = fminf(fmaxf(x + 3.0f, 0.0f), 6.0f);
  return x * t * (1.0f/6.0f);
}

// ---- weight prep -----------------------------------------------------------
__global__ __launch_bounds__(256) void k_wprep(
    const float* __restrict__ wq, const float* __restrict__ wk,
    const float* __restrict__ wv, const float* __restrict__ bq,
    const float* __restrict__ bk, const float* __restrict__ bv,
    const float* __restrict__ w1, const float* __restrict__ w3,
    bf16* __restrict__ wbf2, float* __restrict__ biasc,
    bf16* __restrict__ w1b, bf16* __restrict__ w3b)
{
  const int idx = blockIdx.x*256 + (int)threadIdx.x;
  if (idx < 384)
    biasc[idx] = (idx < 128) ? bq[idx] : (idx < 256 ? bk[idx-128] : bv[idx-256]);
  if (idx < 98304) {
    w1b[idx] = f2b(w1[idx]);
    w3b[idx] = f2b(w3[idx]);
  }
  if (idx < 384*1152) {
    const int c = idx / 1152, rem = idx % 1152;
    const int tap = rem >> 7, ci = rem & 127;
    const float* wsrc = (c < 128) ? wq : (c < 256 ? wk : wv);
    const int cl = (c < 128) ? c : (c < 256 ? c-128 : c-256);
    wbf2[idx] = f2b(wsrc[(size_t)cl*1152 + ci*9 + tap]);
  }
}

// ---- NCHW fp32 -> NHWC bf16 ------------------------------------------------
__global__ __launch_bounds__(256) void k_nhwc(
    const float* __restrict__ refB, const float* __restrict__ othB,
    bf16* __restrict__ nh)
{
  const int pt = blockIdx.x & 127;
  const int sidx = blockIdx.x >> 7;
  const float* src = sidx ? othB : refB;
  __shared__ unsigned short t[128][130];
  const int tid = threadIdx.x;
  const int px4 = (tid & 31) * 4;
  const int cq = tid >> 5;
  #pragma unroll
  for (int cb = 0; cb < 16; ++cb) {
    const int c = cb*8 + cq;
    const float4 f = *(const float4*)(src + (size_t)c*NPIX + pt*128 + px4);
    t[px4+0][c] = f2bu(f.x); t[px4+1][c] = f2bu(f.y);
    t[px4+2][c] = f2bu(f.z); t[px4+3][c] = f2bu(f.w);
  }
  __syncthreads();
  bf16* op = nh + (size_t)sidx*NPIX*128 + (size_t)pt*128*128;
  #pragma unroll
  for (int i = tid; i < 2048; i += 256) {
    const int p = i >> 4;
    const int k = i & 15;
    const unsigned short* tp = &t[p][k*8];
    uint4 v;
    v.x = ((unsigned)tp[1]<<16)|tp[0];
    v.y = ((unsigned)tp[3]<<16)|tp[2];
    v.z = ((unsigned)tp[5]<<16)|tp[4];
    v.w = ((unsigned)tp[7]<<16)|tp[6];
    *(uint4*)(op + (size_t)p*128 + k*8) = v;
  }
}

// ---- MFMA implicit-GEMM 3x3 conv: 32-co tiles for occupancy ----------------
// grid 1536 = 12 tiles(32co) x 128 rows; wave = (co-half, px-half)
#define CSTR 40
#define RSTR 5200   // 130*40
__global__ __launch_bounds__(256) void k_conv(
    const bf16* __restrict__ nh, const bf16* __restrict__ wbf2,
    const float* __restrict__ biasc,
    bf16* __restrict__ kvbuf, bf16* __restrict__ qbuf)
{
  const int y = blockIdx.x & 127;
  const int tile = blockIdx.x >> 7;            // 0..11
  const bf16* src = nh + (size_t)((tile < 4) ? 0 : 1)*NPIX*128;
  const int c0 = (tile < 4) ? tile*32 : 128 + (tile-4)*32;
  __shared__ unsigned short lds[3*RSTR];
  const int tid = threadIdx.x;
  const int lane = tid & 63;
  const int wv4 = tid >> 6;
  const int cw = c0 + (wv4 & 1)*16;            // 2 co-halves of 16
  const int gbase = (wv4 >> 1)*4;              // 2 px-halves of 64
  const int qd = lane >> 4;
  const int l15 = lane & 15;

  f32x4 acc[4];
  #pragma unroll
  for (int g=0; g<4; ++g) acc[g] = (f32x4){0.f,0.f,0.f,0.f};

  if (tid < 192) {
    const int row = tid / 64;
    const int col = ((tid >> 5) & 1) ? 129 : 0;
    const int ci = tid & 31;
    lds[(row*130 + col)*CSTR + ci] = 0;
  }

  const int sx = tid & 127;
  const int sp = tid >> 7;
  const int ldsw = (sx + 1)*CSTR + sp*16;
  const uint4 z4 = make_uint4(0u,0u,0u,0u);

  uint4 cur[3][2], nxt[3][2];
  #pragma unroll
  for (int row = 0; row < 3; ++row) {
    const int yy = y + row - 1;
    if (yy >= 0 && yy < HH) {
      const bf16* p = src + (size_t)(yy*WW + sx)*128 + sp*16;
      cur[row][0] = *(const uint4*)(p);
      cur[row][1] = *(const uint4*)(p + 8);
    } else { cur[row][0] = z4; cur[row][1] = z4; }
  }

  #pragma unroll
  for (int cb = 0; cb < 4; ++cb) {
    __syncthreads();
    #pragma unroll
    for (int row = 0; row < 3; ++row) {
      *(uint4*)&lds[row*RSTR + ldsw]     = cur[row][0];
      *(uint4*)&lds[row*RSTR + ldsw + 8] = cur[row][1];
    }
    __syncthreads();
    if (cb < 3) {
      #pragma unroll
      for (int row = 0; row < 3; ++row) {
        const int yy = y + row - 1;
        if (yy >= 0 && yy < HH) {
          const bf16* p = src + (size_t)(yy*WW + sx)*128 + (cb+1)*32 + sp*16;
          nxt[row][0] = *(const uint4*)(p);
          nxt[row][1] = *(const uint4*)(p + 8);
        } else { nxt[row][0] = z4; nxt[row][1] = z4; }
      }
    }
    #pragma unroll
    for (int tap = 0; tap < 9; ++tap) {
      const int trow = tap/3, kx = tap%3;
      const short8 af = *(const short8*)(wbf2
          + (size_t)(cw + l15)*1152 + tap*128 + cb*32 + qd*8);
      const int bbase = trow*RSTR + (l15 + kx)*CSTR + qd*8;
      #pragma unroll
      for (int g = 0; g < 4; ++g) {
        const short8 bfr = *(const short8*)&lds[bbase + (gbase+g)*16*CSTR];
        acc[g] = __builtin_amdgcn_mfma_f32_16x16x32_bf16(af, bfr, acc[g], 0, 0, 0);
      }
    }
    #pragma unroll
    for (int row = 0; row < 3; ++row) {
      cur[row][0] = nxt[row][0];
      cur[row][1] = nxt[row][1];
    }
  }
  #pragma unroll
  for (int r = 0; r < 4; ++r) {
    const int c = cw + qd*4 + r;
    const int gg = c / 24, rr = c % 24;
    bf16* outp = (rr < 8) ? (qbuf + (size_t)(gg*8 + rr)*NPIX)
                          : (kvbuf + (size_t)(gg*16 + (rr-8))*NPIX);
    const float bias = biasc[c];
    #pragma unroll
    for (int g = 0; g < 4; ++g)
      outp[y*WW + (gbase+g)*16 + l15] = f2b(acc[g][r] + bias);
  }
}

// ---- merged att stage: br0 = qkv KV-reduce, br1 = ms k/v, br2 = msq --------
#define KVSTR 520
#define ATT_SMEM_BYTES 20160
__global__ __launch_bounds__(256) void k_att_ms(
    const bf16* __restrict__ kvbuf, const bf16* __restrict__ qbuf,
    const float* __restrict__ adw, const float* __restrict__ apw,
    float* __restrict__ part, bf16* __restrict__ msq)
{
  __shared__ __align__(16) unsigned char smem[ATT_SMEM_BYTES];
  const int br = blockIdx.x % 3;
  const int sub = blockIdx.x / 3;
  const int tid = threadIdx.x;
  const int lane = tid & 63;
  const int w = tid >> 6;
  const int qd = lane >> 4, l15 = lane & 15;

  if (br == 0) {
    // ---- qkv KV-reduce via MFMA (g0=0) ----
    const int s = sub & 31;
    const int gl = sub >> 5;
    const bf16* bp = kvbuf + (size_t)gl*16*NPIX;
    float (*redm)[9][8] = (float(*)[9][8])smem;
    const int k0 = s*512 + w*128 + qd*8;
    const bf16* ap = bp + (size_t)(8 + (l15 & 7))*NPIX + k0;
    const bf16* bk = bp + (size_t)(l15 & 7)*NPIX + k0;
    const short8 ones8 = {0x3F80,0x3F80,0x3F80,0x3F80,0x3F80,0x3F80,0x3F80,0x3F80};
    f32x4 mac = (f32x4){0.f,0.f,0.f,0.f};
    #pragma unroll
    for (int m = 0; m < 4; ++m) {
      short8 av = *(const short8*)(ap + m*32);
      if (l15 == 8) av = ones8;
      uint4 bu = *(const uint4*)(bk + m*32);
      bu.x = relu2(bu.x); bu.y = relu2(bu.y);
      bu.z = relu2(bu.z); bu.w = relu2(bu.w);
      const short8 bv = __builtin_bit_cast(short8, bu);
      mac = __builtin_amdgcn_mfma_f32_16x16x32_bf16(av, bv, mac, 0, 0, 0);
    }
    #pragma unroll
    for (int r = 0; r < 4; ++r) {
      const int row = qd*4 + r;
      if (l15 < 8 && row < 9) redm[w][row][l15] = mac[r];
    }
    __syncthreads();
    if (tid < 72)
      part[((size_t)gl*32 + s)*72 + tid] =
          redm[0][tid>>3][tid&7] + redm[1][tid>>3][tid&7]
        + redm[2][tid>>3][tid&7] + redm[3][tid>>3][tid&7];

  } else if (br == 1) {
    // ---- ms k/v: two-phase dw5x5 + pw8x8 + relu + MFMA KV-reduce ----
    const int t  = sub & 31;
    const int jj = sub >> 5;
    unsigned short (*sIn)[1056] = (unsigned short(*)[1056])smem;
    float (*dww)[25] = (float(*)[25])(smem + 16896);
    float (*pww)[8]  = (float(*)[8])(smem + 18496);
    float (*redm)[9][8] = (float(*)[9][8])(smem + 19008);
    unsigned short* kvA = (unsigned short*)smem;      // aliases sIn after barrier
    unsigned short* kvB = kvA + 9*KVSTR;

    for (int i = tid; i < 400; i += 256) {
      const int ch = i/25, kk5 = i%25;
      dww[ch][kk5] = adw[(24*jj + 8 + ch)*25 + kk5];
    }
    for (int i = tid; i < 128; i += 256) {
      const int r = i>>3, ii = i&7;
      pww[r][ii] = apw[(24*jj + 8 + r)*8 + ii];
    }
    if (tid < 64) {                    // zero x-pads (persist across phases)
      const int ch = tid & 7, r = tid >> 3;
      *(unsigned int*)&sIn[ch][r*132 + 0] = 0u;
      *(unsigned int*)&sIn[ch][r*132 + 130] = 0u;
    }
    const int y0 = t*4 - 2;
    const int xp = (tid & 63)*2;       // 2 output px per thread
    const int row = tid >> 6;          // output row in tile (0..3)
    float ko[8][2], mv[8][2];

    // ---- phase A: k-source channels (rows jj*16+0..7) ----
    #pragma unroll
    for (int rep = 0; rep < 4; ++rep) {
      const int L = rep*256 + tid;
      const int col8 = L & 15;
      const int rowc = L >> 4;
      const int r = rowc >> 3, ch = rowc & 7;
      const int gy = y0 + r;
      uint4 pk = make_uint4(0u,0u,0u,0u);
      if (gy >= 0 && gy < HH)
        pk = *(const uint4*)(kvbuf + (size_t)(jj*16 + ch)*NPIX + gy*WW + col8*8);
      unsigned short* dst = &sIn[ch][r*132 + 2 + col8*8];
      *(unsigned int*)(dst + 0) = pk.x;
      *(unsigned int*)(dst + 2) = pk.y;
      *(unsigned int*)(dst + 4) = pk.z;
      *(unsigned int*)(dst + 6) = pk.w;
    }
    __syncthreads();
    #pragma unroll
    for (int e=0;e<8;++e){ ko[e][0]=0.f; ko[e][1]=0.f; }
    #pragma unroll
    for (int c=0;c<8;++c) {
      float o0=0.f, o1=0.f;
      #pragma unroll
      for (int rr=0; rr<5; ++rr) {
        const unsigned int* rp = (const unsigned int*)&sIn[c][(row+rr)*132 + xp];
        float v0,v1,v2,v3,v4,v5;
        bf2x(rp[0], v0, v1); bf2x(rp[1], v2, v3); bf2x(rp[2], v4, v5);
        const float* wr = &dww[c][rr*5];
        o0 += wr[0]*v0; o0 += wr[1]*v1; o0 += wr[2]*v2; o0 += wr[3]*v3; o0 += wr[4]*v4;
        o1 += wr[0]*v1; o1 += wr[1]*v2; o1 += wr[2]*v3; o1 += wr[3]*v4; o1 += wr[4]*v5;
      }
      #pragma unroll
      for (int e=0;e<8;++e){ ko[e][0] += pww[e][c]*o0; ko[e][1] += pww[e][c]*o1; }
    }
    #pragma unroll
    for (int e=0;e<8;++e){ ko[e][0]=fmaxf(ko[e][0],0.f); ko[e][1]=fmaxf(ko[e][1],0.f); }
    __syncthreads();

    // ---- phase B: v-source channels (rows jj*16+8..15) ----
    #pragma unroll
    for (int rep = 0; rep < 4; ++rep) {
      const int L = rep*256 + tid;
      const int col8 = L & 15;
      const int rowc = L >> 4;
      const int r = rowc >> 3, ch = rowc & 7;
      const int gy = y0 + r;
      uint4 pk = make_uint4(0u,0u,0u,0u);
      if (gy >= 0 && gy < HH)
        pk = *(const uint4*)(kvbuf + (size_t)(jj*16 + 8 + ch)*NPIX + gy*WW + col8*8);
      unsigned short* dst = &sIn[ch][r*132 + 2 + col8*8];
      *(unsigned int*)(dst + 0) = pk.x;
      *(unsigned int*)(dst + 2) = pk.y;
      *(unsigned int*)(dst + 4) = pk.z;
      *(unsigned int*)(dst + 6) = pk.w;
    }
    __syncthreads();
    {
      float dv[8][2];
      #pragma unroll
      for (int c=0;c<8;++c) {
        float o0=0.f, o1=0.f;
        #pragma unroll
        for (int rr=0; rr<5; ++rr) {
          const unsigned int* rp = (const unsigned int*)&sIn[c][(row+rr)*132 + xp];
          float v0,v1,v2,v3,v4,v5;
          bf2x(rp[0], v0, v1); bf2x(rp[1], v2, v3); bf2x(rp[2], v4, v5);
          const float* wr = &dww[8+c][rr*5];
          o0 += wr[0]*v0; o0 += wr[1]*v1; o0 += wr[2]*v2; o0 += wr[3]*v3; o0 += wr[4]*v4;
          o1 += wr[0]*v1; o1 += wr[1]*v2; o1 += wr[2]*v3; o1 += wr[3]*v4; o1 += wr[4]*v5;
        }
        dv[c][0]=o0; dv[c][1]=o1;
      }
      #pragma unroll
      for (int d=0;d<8;++d) {
        float v0=0.f, v1=0.f;
        #pragma unroll
        for (int i=0;i<8;++i){ v0 += pww[8+d][i]*dv[i][0]; v1 += pww[8+d][i]*dv[i][1]; }
        mv[d][0]=v0; mv[d][1]=v1;
      }
    }
    __syncthreads();   // all reads of sIn/dww done before aliasing kvA/kvB

    const int px = row*128 + xp;       // even -> aligned u32 writes
    #pragma unroll
    for (int e=0;e<8;++e)
      *(unsigned int*)&kvB[e*KVSTR + px] =
          ((unsigned int)f2bu(ko[e][1]) << 16) | f2bu(ko[e][0]);
    #pragma unroll
    for (int d=0;d<8;++d)
      *(unsigned int*)&kvA[d*KVSTR + px] =
          ((unsigned int)f2bu(mv[d][1]) << 16) | f2bu(mv[d][0]);
    *(unsigned int*)&kvA[8*KVSTR + px] = 0x3F803F80u;   // ones row -> ksum
    __syncthreads();

    const int ra = (l15 < 9) ? l15 : 0;    // clamp junk lanes in-bounds
    const int rb = l15 & 7;
    f32x4 mac = (f32x4){0.f,0.f,0.f,0.f};
    #pragma unroll
    for (int m = 0; m < 4; ++m) {
      const int kk = w*128 + m*32 + qd*8;
      const short8 av = *(const short8*)&kvA[ra*KVSTR + kk];
      const short8 bv = *(const short8*)&kvB[rb*KVSTR + kk];
      mac = __builtin_amdgcn_mfma_f32_16x16x32_bf16(av, bv, mac, 0, 0, 0);
    }
    #pragma unroll
    for (int r = 0; r < 4; ++r) {
      const int rw = qd*4 + r;
      if (l15 < 8 && rw < 9) redm[w][rw][l15] = mac[r];
    }
    __syncthreads();
    if (tid < 72)
      part[((size_t)(16+jj)*32 + t)*72 + tid] =
          redm[0][tid>>3][tid&7] + redm[1][tid>>3][tid&7]
        + redm[2][tid>>3][tid&7] + redm[3][tid>>3][tid&7];

  } else {
    // ---- ms q: dw5x5 + pw8x8 (px-pair reads) ----
    const int t  = sub & 31;
    const int jj = sub >> 5;
    unsigned short (*sIn)[1056] = (unsigned short(*)[1056])smem;
    float (*dww)[25] = (float(*)[25])(smem + 16896);
    float (*pww)[8]  = (float(*)[8])(smem + 17696);

    for (int i = tid; i < 200; i += 256)
      dww[i/25][i%25] = adw[(24*jj + i/25)*25 + (i%25)];
    if (tid < 64)
      pww[tid>>3][tid&7] = apw[(24*jj + (tid>>3))*8 + (tid&7)];
    if (tid < 64) {
      const int ch = tid & 7, r = tid >> 3;
      *(unsigned int*)&sIn[ch][r*132 + 0] = 0u;
      *(unsigned int*)&sIn[ch][r*132 + 130] = 0u;
    }
    const int y0 = t*4 - 2;
    #pragma unroll
    for (int rep = 0; rep < 4; ++rep) {
      const int L = rep*256 + tid;
      const int col8 = L & 15;
      const int rowc = L >> 4;
      const int r = rowc >> 3, ch = rowc & 7;
      const int gy = y0 + r;
      uint4 pk = make_uint4(0u,0u,0u,0u);
      if (gy >= 0 && gy < HH)
        pk = *(const uint4*)(qbuf + (size_t)(jj*8 + ch)*NPIX + gy*WW + col8*8);
      unsigned short* dst = &sIn[ch][r*132 + 2 + col8*8];
      *(unsigned int*)(dst + 0) = pk.x;
      *(unsigned int*)(dst + 2) = pk.y;
      *(unsigned int*)(dst + 4) = pk.z;
      *(unsigned int*)(dst + 6) = pk.w;
    }
    __syncthreads();

    const int xp = (tid & 63)*2;
    const int row = tid >> 6;
    const int row0 = t*4 + row;

    float dq[8][2];
    #pragma unroll
    for (int c=0;c<8;++c) {
      float o0=0.f, o1=0.f;
      #pragma unroll
      for (int rr=0; rr<5; ++rr) {
        const unsigned int* rp = (const unsigned int*)&sIn[c][(row+rr)*132 + xp];
        float v0,v1,v2,v3,v4,v5;
        bf2x(rp[0], v0, v1); bf2x(rp[1], v2, v3); bf2x(rp[2], v4, v5);
        const float* wr = &dww[c][rr*5];
        o0 += wr[0]*v0; o0 += wr[1]*v1; o0 += wr[2]*v2; o0 += wr[3]*v3; o0 += wr[4]*v4;
        o1 += wr[0]*v1; o1 += wr[1]*v2; o1 += wr[2]*v3; o1 += wr[3]*v4; o1 += wr[4]*v5;
      }
      dq[c][0]=o0; dq[c][1]=o1;
    }
    #pragma unroll
    for (int e=0;e<8;++e) {
      float o0=0.f, o1=0.f;
      #pragma unroll
      for (int i=0;i<8;++i){ o0 += pww[e][i]*dq[i][0]; o1 += pww[e][i]*dq[i][1]; }
      *(unsigned int*)(msq + (size_t)(jj*8 + e)*NPIX + row0*WW + xp) =
          ((unsigned int)f2bu(o1) << 16) | f2bu(o0);
    }
  }
}

// ---- fold proj weights: absorbs split-sum + writes kv denominators ---------
__global__ __launch_bounds__(256) void k_fold2(
    const float* __restrict__ pjw, const float* __restrict__ part,
    const float* __restrict__ g1, const float* __restrict__ bb1,
    const float* __restrict__ m1, const float* __restrict__ v1,
    bf16* __restrict__ wtb, float* __restrict__ bias2, float* __restrict__ kvf)
{
  const int co = blockIdx.x;
  const int ge = (int)threadIdx.x;
  const int g = ge >> 3, e = ge & 7;
  float kv[8];
  #pragma unroll
  for (int d=0;d<8;++d) kv[d] = 0.f;
  for (int s = 0; s < 32; ++s) {
    const float* pp = part + ((size_t)g*32 + s)*72;
    #pragma unroll
    for (int d=0;d<8;++d) kv[d] += pp[d*8 + e];
  }
  const float sc = g1[co] * rsqrtf(v1[co] + 1e-5f);
  float acc = 0.f;
  #pragma unroll
  for (int d = 0; d < 8; ++d)
    acc += pjw[co*256 + g*8 + d] * kv[d];
  wtb[(size_t)co*256 + ge] = f2b(sc * acc);
  if (ge == 0) bias2[co] = bb1[co] - m1[co]*sc;
  if (co < 32 && ge < 8) {
    float s8 = 0.f;
    for (int s = 0; s < 32; ++s) s8 += part[((size_t)co*32 + s)*72 + 64 + ge];
    kvf[(size_t)co*72 + 64 + ge] = s8;
  }
}

// ---- MFMA att+proj ---------------------------------------------------------
__global__ __launch_bounds__(256) void k_proj_m(
    const bf16* __restrict__ qbuf, const bf16* __restrict__ msq,
    const float* __restrict__ kvf, const bf16* __restrict__ wtb,
    const float* __restrict__ bias2, const float* __restrict__ refB,
    float* __restrict__ attd)
{
  const int n0 = blockIdx.x * 64;
  __shared__ unsigned short lds[64*CSTR];
  __shared__ float kvden[32][8];
  __shared__ float b2s[128];
  const int tid = threadIdx.x;
  kvden[tid>>3][tid&7] = kvf[(size_t)(tid>>3)*72 + 64 + (tid&7)];
  if (tid < 128) b2s[tid] = bias2[tid];
  const int lane = tid & 63;
  const int w = tid >> 6;
  const int qd = lane >> 4, l15 = lane & 15;
  const int px = tid & 63;

  f32x4 acc[2][4];
  #pragma unroll
  for (int t=0;t<2;++t)
    #pragma unroll
    for (int g=0;g<4;++g) acc[t][g] = (f32x4){0.f,0.f,0.f,0.f};

  for (int cb = 0; cb < 8; ++cb) {
    __syncthreads();
    const int g = cb*4 + w;
    const bf16* base = (g < 16) ? qbuf + (size_t)g*8*NPIX
                                : msq + (size_t)(g-16)*8*NPIX;
    float q8[8];
    #pragma unroll
    for (int e=0;e<8;++e) q8[e] = fmaxf(b2f(base[(size_t)e*NPIX + n0 + px]), 0.f);
    float den = 1e-15f;
    #pragma unroll
    for (int e=0;e<8;++e) den += kvden[g][e]*q8[e];
    const float inv = 1.0f/den;
    uint4 pk;
    pk.x = ((unsigned int)f2bu(q8[1]*inv) << 16) | f2bu(q8[0]*inv);
    pk.y = ((unsigned int)f2bu(q8[3]*inv) << 16) | f2bu(q8[2]*inv);
    pk.z = ((unsigned int)f2bu(q8[5]*inv) << 16) | f2bu(q8[4]*inv);
    pk.w = ((unsigned int)f2bu(q8[7]*inv) << 16) | f2bu(q8[6]*inv);
    *(uint4*)&lds[px*CSTR + w*8] = pk;
    __syncthreads();
    const short8 af0 = *(const short8*)(wtb + (size_t)(w*32 + l15)*256 + cb*32 + qd*8);
    const short8 af1 = *(const short8*)(wtb + (size_t)(w*32 + 16 + l15)*256 + cb*32 + qd*8);
    #pragma unroll
    for (int gg = 0; gg < 4; ++gg) {
      const short8 bfr = *(const short8*)&lds[(gg*16 + l15)*CSTR + qd*8];
      acc[0][gg] = __builtin_amdgcn_mfma_f32_16x16x32_bf16(af0, bfr, acc[0][gg], 0, 0, 0);
      acc[1][gg] = __builtin_amdgcn_mfma_f32_16x16x32_bf16(af1, bfr, acc[1][gg], 0, 0, 0);
    }
  }
  #pragma unroll
  for (int t = 0; t < 2; ++t) {
    #pragma unroll
    for (int r = 0; r < 4; ++r) {
      const int co = w*32 + t*16 + qd*4 + r;
      const float bi = b2s[co];
      #pragma unroll
      for (int gg = 0; gg < 4; ++gg) {
        const int pxg = n0 + gg*16 + l15;
        attd[(size_t)co*NPIX + pxg] = refB[(size_t)co*NPIX + pxg] + acc[t][gg][r] + bi;
      }
    }
  }
}

// ---- MFMA 1x1 mb1 ----------------------------------------------------------
__global__ __launch_bounds__(256) void k_mb1_m(
    const float* __restrict__ attd, const bf16* __restrict__ w1b,
    const float* __restrict__ bias, bf16* __restrict__ h1s, int s)
{
  const int pxt = blockIdx.x & 127;
  const int cot = blockIdx.x >> 7;
  const int n0 = pxt*128;
  __shared__ unsigned short lds[128*CSTR];
  const int tid = threadIdx.x;
  const int lane = tid & 63;
  const int wv4 = tid >> 6;
  const int co16 = s*192 + cot*64 + wv4*16;
  const int qd = lane >> 4, l15 = lane & 15;
  f32x4 acc[8];
  #pragma unroll
  for (int g=0; g<8; ++g) acc[g] = (f32x4){0.f,0.f,0.f,0.f};
  const int sx = tid & 127, sp = tid >> 7;
  for (int cb = 0; cb < 4; ++cb) {
    __syncthreads();
    const float* rp = attd + (size_t)(cb*32)*NPIX + n0 + sx;
    for (int cp = sp; cp < 16; cp += 2) {
      const float a0 = rp[(size_t)(2*cp)*NPIX];
      const float a1 = rp[(size_t)(2*cp+1)*NPIX];
      *(unsigned int*)&lds[sx*CSTR + 2*cp] =
          ((unsigned int)f2bu(a1) << 16) | f2bu(a0);
    }
    __syncthreads();
    const short8 af = *(const short8*)(w1b + (size_t)(co16 + l15)*128 + cb*32 + qd*8);
    #pragma unroll
    for (int g = 0; g < 8; ++g) {
      const short8 bfr = *(const short8*)&lds[(g*16 + l15)*CSTR + qd*8];
      acc[g] = __builtin_amdgcn_mfma_f32_16x16x32_bf16(af, bfr, acc[g], 0, 0, 0);
    }
  }
  #pragma unroll
  for (int r = 0; r < 4; ++r) {
    const int co = co16 + qd*4 + r;
    const float bi = bias[co];
    bf16* op = h1s + (size_t)(co - s*192)*NPIX + n0;
    #pragma unroll
    for (int g = 0; g < 8; ++g)
      op[g*16 + l15] = f2b(hswish(acc[g][r] + bi));
  }
}

// ---- LDS-tiled 3x3 depthwise mb2 + hswish ----------------------------------
// grid: 768 = 192 ch * 4 rowtiles(32); data at tile col 2 (aligned u32 writes)
__global__ __launch_bounds__(256) void k_mb2(
    const bf16* __restrict__ h1s, const float* __restrict__ w,
    const float* __restrict__ bias, bf16* __restrict__ h2s, int s)
{
  const int rt = blockIdx.x & 3;
  const int cl = blockIdx.x >> 2;          // 0..191
  const int cg = s*192 + cl;
  __shared__ unsigned short tile[34][132];
  __shared__ float wc9[9];
  __shared__ float bsh[1];
  const int tid = threadIdx.x;
  if (tid < 9) wc9[tid] = w[cg*9 + tid];
  if (tid == 9) bsh[0] = bias[cg];
  if (tid < 136) {
    const int r = tid >> 2;
    const int csel = tid & 3;
    const int c = (csel == 0) ? 0 : (csel == 1) ? 1 : (csel == 2) ? 130 : 131;
    tile[r][c] = 0;
  }
  const int y0 = rt*32;
  const bf16* in = h1s + (size_t)cl*NPIX;
  for (int i = tid; i < 544; i += 256) {     // 34 rows * 16 uint4
    const int rr = i >> 4, c8 = i & 15;
    const int gy = y0 - 1 + rr;
    uint4 pk = make_uint4(0u,0u,0u,0u);
    if (gy >= 0 && gy < HH) pk = *(const uint4*)(in + gy*WW + c8*8);
    unsigned short* dst = &tile[rr][2 + c8*8];
    *(unsigned int*)(dst+0)=pk.x; *(unsigned int*)(dst+2)=pk.y;
    *(unsigned int*)(dst+4)=pk.z; *(unsigned int*)(dst+6)=pk.w;
  }
  __syncthreads();
  const int x = tid & 127;
  const int rb = (tid >> 7) * 16;
  float a0,b0,c0,a1,b1,c1,a2,b2,c2;
  {
    const unsigned short* p = &tile[rb][x+1];
    a0=u16f(p[0]); b0=u16f(p[1]); c0=u16f(p[2]);
    p = &tile[rb+1][x+1];
    a1=u16f(p[0]); b1=u16f(p[1]); c1=u16f(p[2]);
  }
  bf16* op = h2s + (size_t)cl*NPIX + (y0+rb)*WW + x;
  #pragma unroll
  for (int j = 0; j < 16; ++j) {
    const unsigned short* p = &tile[rb+j+2][x+1];
    a2=u16f(p[0]); b2=u16f(p[1]); c2=u16f(p[2]);
    float acc = bsh[0] + wc9[0]*a0 + wc9[1]*b0 + wc9[2]*c0
                       + wc9[3]*a1 + wc9[4]*b1 + wc9[5]*c1
                       + wc9[6]*a2 + wc9[7]*b2 + wc9[8]*c2;
    op[j*WW] = f2b(hswish(acc));
    a0=a1; b0=b1; c0=c1; a1=a2; b1=b2; c1=c2;
  }
}

// ---- merged mb3(s3 in 0..2) + mb1(s1) --------------------------------------
// grid 640: blocks <256 -> mb3 accumulate, >=256 -> mb1
__global__ __launch_bounds__(256) void k_mb31(
    const bf16* __restrict__ h2s, const bf16* __restrict__ w3b,
    float* __restrict__ accb, int s3,
    const float* __restrict__ attd, const bf16* __restrict__ w1b,
    const float* __restrict__ bias1, bf16* __restrict__ h1s, int s1)
{
  __shared__ unsigned short lds[128*CSTR];
  const int tid = threadIdx.x;
  const int lane = tid & 63;
  const int wv4 = tid >> 6;
  const int qd = lane >> 4, l15 = lane & 15;
  const int sx = tid & 127, sp = tid >> 7;

  if (blockIdx.x < 256) {
    // ---- mb3 partial ----
    const int pxt = blockIdx.x & 127;
    const int cot = blockIdx.x >> 7;
    const int n0 = pxt*128;
    const int co16 = cot*64 + wv4*16;
    f32x4 acc[8];
    #pragma unroll
    for (int g=0; g<8; ++g) acc[g] = (f32x4){0.f,0.f,0.f,0.f};
    for (int cb = 0; cb < 6; ++cb) {
      __syncthreads();
      const bf16* rp = h2s + (size_t)(cb*32)*NPIX + n0 + sx;
      for (int cp = sp; cp < 16; cp += 2) {
        const unsigned short a0 = bbits(rp[(size_t)(2*cp)*NPIX]);
        const unsigned short a1 = bbits(rp[(size_t)(2*cp+1)*NPIX]);
        *(unsigned int*)&lds[sx*CSTR + 2*cp] = ((unsigned int)a1 << 16) | a0;
      }
      __syncthreads();
      const short8 af = *(const short8*)(w3b + (size_t)(co16 + l15)*768 + s3*192 + cb*32 + qd*8);
      #pragma unroll
      for (int g = 0; g < 8; ++g) {
        const short8 bfr = *(const short8*)&lds[(g*16 + l15)*CSTR + qd*8];
        acc[g] = __builtin_amdgcn_mfma_f32_16x16x32_bf16(af, bfr, acc[g], 0, 0, 0);
      }
    }
    #pragma unroll
    for (int r = 0; r < 4; ++r) {
      const int co = co16 + qd*4 + r;
      float* op = accb + (size_t)co*NPIX + n0;
      if (s3 == 0) {
        #pragma unroll
        for (int g = 0; g < 8; ++g) op[g*16 + l15] = acc[g][r];
      } else {
        #pragma unroll
        for (int g = 0; g < 8; ++g) op[g*16 + l15] += acc[g][r];
      }
    }
  } else {
    // ---- mb1 for slab s1 ----
    const int bid = blockIdx.x - 256;
    const int pxt = bid & 127;
    const int cot = bid >> 7;            // 0..2
    const int n0 = pxt*128;
    const int co16 = s1*192 + cot*64 + wv4*16;
    f32x4 acc[8];
    #pragma unroll
    for (int g=0; g<8; ++g) acc[g] = (f32x4){0.f,0.f,0.f,0.f};
    for (int cb = 0; cb < 4; ++cb) {
      __syncthreads();
      const float* rp = attd + (size_t)(cb*32)*NPIX + n0 + sx;
      for (int cp = sp; cp < 16; cp += 2) {
        const float a0 = rp[(size_t)(2*cp)*NPIX];
        const float a1 = rp[(size_t)(2*cp+1)*NPIX];
        *(unsigned int*)&lds[sx*CSTR + 2*cp] =
            ((unsigned int)f2bu(a1) << 16) | f2bu(a0);
      }
      __syncthreads();
      const short8 af = *(const short8*)(w1b + (size_t)(co16 + l15)*128 + cb*32 + qd*8);
      #pragma unroll
      for (int g = 0; g < 8; ++g) {
        const short8 bfr = *(const short8*)&lds[(g*16 + l15)*CSTR + qd*8];
        acc[g] = __builtin_amdgcn_mfma_f32_16x16x32_bf16(af, bfr, acc[g], 0, 0, 0);
      }
    }
    #pragma unroll
    for (int r = 0; r < 4; ++r) {
      const int co = co16 + qd*4 + r;
      const float bi = bias1[co];
      bf16* op = h1s + (size_t)(co - s1*192)*NPIX + n0;
      #pragma unroll
      for (int g = 0; g < 8; ++g)
        op[g*16 + l15] = f2b(hswish(acc[g][r] + bi));
    }
  }
}

// ---- final mb3 (s=3) + BN2 + residual into attd ----------------------------
__global__ __launch_bounds__(256) void k_mb3f(
    const bf16* __restrict__ h2s, const bf16* __restrict__ w3b,
    const float* __restrict__ accb,
    const float* __restrict__ g2, const float* __restrict__ b2p,
    const float* __restrict__ m2, const float* __restrict__ v2,
    float* __restrict__ attd)
{
  const int pxt = blockIdx.x & 127;
  const int cot = blockIdx.x >> 7;
  const int n0 = pxt*128;
  __shared__ unsigned short lds[128*CSTR];
  const int tid = threadIdx.x;
  const int lane = tid & 63;
  const int wv4 = tid >> 6;
  const int co16 = cot*64 + wv4*16;
  const int qd = lane >> 4, l15 = lane & 15;
  f32x4 acc[8];
  #pragma unroll
  for (int g=0; g<8; ++g) acc[g] = (f32x4){0.f,0.f,0.f,0.f};
  const int sx = tid & 127, sp = tid >> 7;
  for (int cb = 0; cb < 6; ++cb) {
    __syncthreads();
    const bf16* rp = h2s + (size_t)(cb*32)*NPIX + n0 + sx;
    for (int cp = sp; cp < 16; cp += 2) {
      const unsigned short a0 = bbits(rp[(size_t)(2*cp)*NPIX]);
      const unsigned short a1 = bbits(rp[(size_t)(2*cp+1)*NPIX]);
      *(unsigned int*)&lds[sx*CSTR + 2*cp] = ((unsigned int)a1 << 16) | a0;
    }
    __syncthreads();
    const short8 af = *(const short8*)(w3b + (size_t)(co16 + l15)*768 + 576 + cb*32 + qd*8);
    #pragma unroll
    for (int g = 0; g < 8; ++g) {
      const short8 bfr = *(const short8*)&lds[(g*16 + l15)*CSTR + qd*8];
      acc[g] = __builtin_amdgcn_mfma_f32_16x16x32_bf16(af, bfr, acc[g], 0, 0, 0);
    }
  }
  #pragma unroll
  for (int r = 0; r < 4; ++r) {
    const int co = co16 + qd*4 + r;
    const float scale = g2[co] * rsqrtf(v2[co] + 1e-5f);
    const float bb = b2p[co];
    const float mm = m2[co];
    #pragma unroll
    for (int g = 0; g < 8; ++g) {
      const size_t idx = (size_t)co*NPIX + n0 + g*16 + l15;
      const float val = accb[idx] + acc[g][r];
      const float y = (val - mm)*scale + bb;
      attd[idx] = attd[idx] + y;
    }
  }
}

extern "C" void kernel_launch(void* const* d_in, const int* in_sizes, int n_in,
                              void* d_out, int out_size, void* d_ws, size_t ws_size,
                              hipStream_t stream)
{
  const float* ref = (const float*)d_in[0];
  const float* oth = (const float*)d_in[1];
  const float* wq  = (const float*)d_in[2];
  const float* bq  = (const float*)d_in[3];
  const float* wk  = (const float*)d_in[4];
  const float* bk  = (const float*)d_in[5];
  const float* wv  = (const float*)d_in[6];
  const float* bv  = (const float*)d_in[7];
  const float* adw = (const float*)d_in[8];
  const float* apw = (const float*)d_in[9];
  const float* pjw = (const float*)d_in[10];
  const float* g1  = (const float*)d_in[11];
  const float* b1  = (const float*)d_in[12];
  const float* m1  = (const float*)d_in[13];
  const float* v1  = (const float*)d_in[14];
  const float* w1  = (const float*)d_in[15];
  const float* bb1 = (const float*)d_in[16];
  const float* w2  = (const float*)d_in[17];
  const float* bb2 = (const float*)d_in[18];
  const float* w3  = (const float*)d_in[19];
  const float* g2  = (const float*)d_in[20];
  const float* b2p = (const float*)d_in[21];
  const float* m2  = (const float*)d_in[22];
  const float* v2  = (const float*)d_in[23];

  char* ws = (char*)d_ws;
  bf16*  wbf2  = (bf16*)(ws + 0);
  float* biasc = (float*)(ws + 884736);
  bf16*  w1b   = (bf16*)(ws + 886272);
  bf16*  w3b   = (bf16*)(ws + 1082880);
  bf16*  kvbuf = (bf16*)(ws + 1279488);
  bf16*  qbuf  = (bf16*)(ws + 9668096);
  bf16*  nh    = (bf16*)(ws + 13862400);
  bf16*  msq   = (bf16*)(ws + 13862400);
  float* part  = (float*)(ws + 22251008);
  float* kvf   = (float*)(ws + 22545920);
  bf16*  wtb   = (bf16*)(ws + 22555136);
  float* bias2 = (float*)(ws + 22620672);
  float* accb  = (float*)(ws + 1279488);
  bf16*  h1s   = (bf16*)(ws + 9668096);
  bf16*  h2s   = (bf16*)(ws + 15959552);

  k_wprep<<<1728, 256, 0, stream>>>(wq, wk, wv, bq, bk, bv, w1, w3, wbf2, biasc, w1b, w3b);

  for (int b = 0; b < 4; ++b) {
    const float* refB = ref + (size_t)b*128*NPIX;
    const float* othB = oth + (size_t)b*128*NPIX;
    float* attd = (float*)d_out + (size_t)b*128*NPIX;

    k_nhwc   <<<256,  256, 0, stream>>>(refB, othB, nh);
    k_conv   <<<1536, 256, 0, stream>>>(nh, wbf2, biasc, kvbuf, qbuf);
    k_att_ms <<<1536, 256, 0, stream>>>(kvbuf, qbuf, adw, apw, part, msq);
    k_fold2  <<<128,  256, 0, stream>>>(pjw, part, g1, b1, m1, v1, wtb, bias2, kvf);
    k_proj_m <<<256,  256, 0, stream>>>(qbuf, msq, kvf, wtb, bias2, refB, attd);

    k_mb1_m  <<<384,  256, 0, stream>>>(attd, w1b, bb1, h1s, 0);
    k_mb2    <<<768,  256, 0, stream>>>(h1s, w2, bb2, h2s, 0);
    for (int s = 0; s < 3; ++s) {
      k_mb31 <<<640,  256, 0, stream>>>(h2s, w3b, accb, s, attd, w1b, bb1, h1s, s+1);
      k_mb2  <<<768,  256, 0, stream>>>(h1s, w2, bb2, h2s, s+1);
    }
    k_mb3f   <<<256,  256, 0, stream>>>(h2s, w3b, accb, g2, b2p, m2, v2, attd);
  }
}

// Round 11
// 809.697 us; speedup vs baseline: 1.0478x; 1.0478x over previous
//
#include <hip/hip_runtime.h>
#include <hip/hip_bf16.h>

#define HH 128
#define WW 128
#define NPIX 16384

using bf16 = __hip_bfloat16;
typedef __attribute__((ext_vector_type(8))) short short8;
typedef __attribute__((ext_vector_type(4))) float f32x4;

__device__ __forceinline__ float b2f(bf16 x){ return __bfloat162float(x); }
__device__ __forceinline__ bf16 f2b(float x){ return __float2bfloat16(x); }
__device__ __forceinline__ unsigned short f2bu(float x){
  bf16 h = __float2bfloat16(x);
  return __builtin_bit_cast(unsigned short, h);
}
__device__ __forceinline__ unsigned short bbits(bf16 x){
  return __builtin_bit_cast(unsigned short, x);
}
__device__ __forceinline__ float u16f(unsigned short u){
  return __bfloat162float(__builtin_bit_cast(bf16, u));
}
__device__ __forceinline__ void bf2x(unsigned int u, float& a, float& b){
  a = u16f((unsigned short)(u & 0xffffu));
  b = u16f((unsigned short)(u >> 16));
}
__device__ __forceinline__ unsigned int relu2(unsigned int x){
  unsigned int s = x & 0x80008000u;
  unsigned int t = s >> 15;
  unsigned int m = (t << 16) - t;
  return x & ~m;
}
__device__ __forceinline__ float hswish(float x){
  float t = fminf(fmaxf(x + 3.0f, 0.0f), 6.0f);
  return x * t * (1.0f/6.0f);
}

// ---- weight prep -----------------------------------------------------------
__global__ __launch_bounds__(256) void k_wprep(
    const float* __restrict__ wq, const float* __restrict__ wk,
    const float* __restrict__ wv, const float* __restrict__ bq,
    const float* __restrict__ bk, const float* __restrict__ bv,
    const float* __restrict__ w1, const float* __restrict__ w3,
    bf16* __restrict__ wbf2, float* __restrict__ biasc,
    bf16* __restrict__ w1b, bf16* __restrict__ w3b)
{
  const int idx = blockIdx.x*256 + (int)threadIdx.x;
  if (idx < 384)
    biasc[idx] = (idx < 128) ? bq[idx] : (idx < 256 ? bk[idx-128] : bv[idx-256]);
  if (idx < 98304) {
    w1b[idx] = f2b(w1[idx]);
    w3b[idx] = f2b(w3[idx]);
  }
  if (idx < 384*1152) {
    const int c = idx / 1152, rem = idx % 1152;
    const int tap = rem >> 7, ci = rem & 127;
    const float* wsrc = (c < 128) ? wq : (c < 256 ? wk : wv);
    const int cl = (c < 128) ? c : (c < 256 ? c-128 : c-256);
    wbf2[idx] = f2b(wsrc[(size_t)cl*1152 + ci*9 + tap]);
  }
}

// ---- NCHW fp32 -> NHWC bf16 ------------------------------------------------
__global__ __launch_bounds__(256) void k_nhwc(
    const float* __restrict__ refB, const float* __restrict__ othB,
    bf16* __restrict__ nh)
{
  const int pt = blockIdx.x & 127;
  const int sidx = blockIdx.x >> 7;
  const float* src = sidx ? othB : refB;
  __shared__ unsigned short t[128][130];
  const int tid = threadIdx.x;
  const int px4 = (tid & 31) * 4;
  const int cq = tid >> 5;
  #pragma unroll
  for (int cb = 0; cb < 16; ++cb) {
    const int c = cb*8 + cq;
    const float4 f = *(const float4*)(src + (size_t)c*NPIX + pt*128 + px4);
    t[px4+0][c] = f2bu(f.x); t[px4+1][c] = f2bu(f.y);
    t[px4+2][c] = f2bu(f.z); t[px4+3][c] = f2bu(f.w);
  }
  __syncthreads();
  bf16* op = nh + (size_t)sidx*NPIX*128 + (size_t)pt*128*128;
  #pragma unroll
  for (int i = tid; i < 2048; i += 256) {
    const int p = i >> 4;
    const int k = i & 15;
    const unsigned short* tp = &t[p][k*8];
    uint4 v;
    v.x = ((unsigned)tp[1]<<16)|tp[0];
    v.y = ((unsigned)tp[3]<<16)|tp[2];
    v.z = ((unsigned)tp[5]<<16)|tp[4];
    v.w = ((unsigned)tp[7]<<16)|tp[6];
    *(uint4*)(op + (size_t)p*128 + k*8) = v;
  }
}

// ---- MFMA implicit-GEMM 3x3 conv: 64-px row halves for occupancy -----------
// grid 1536 = 6 tiles(64co) x 128 rows x 2 xhalves; LDS 16320B
#define CSTR 40
#define RSTR2 2720   // 68*40
__global__ __launch_bounds__(256) void k_conv(
    const bf16* __restrict__ nh, const bf16* __restrict__ wbf2,
    const float* __restrict__ biasc,
    bf16* __restrict__ kvbuf, bf16* __restrict__ qbuf)
{
  const int xh = blockIdx.x & 1;
  const int y  = (blockIdx.x >> 1) & 127;
  const int tile = blockIdx.x >> 8;            // 0..5
  const bf16* src = nh + (size_t)((tile < 2) ? 0 : 1)*NPIX*128;
  const int c0 = (tile < 2) ? tile*64 : 128 + (tile-2)*64;
  const int x0 = xh*64;
  __shared__ unsigned short lds[3*RSTR2];
  const int tid = threadIdx.x;
  const int lane = tid & 63;
  const int wv4 = tid >> 6;
  const int cw = c0 + wv4*16;                  // 4 waves x 16 co
  const int qd = lane >> 4;
  const int l15 = lane & 15;

  f32x4 acc[4];
  #pragma unroll
  for (int g=0; g<4; ++g) acc[g] = (f32x4){0.f,0.f,0.f,0.f};

  const uint4 z4 = make_uint4(0u,0u,0u,0u);
  // staging slots: 792 = 3 rows * 66 px * 4 q(8ci); local px 0 <-> gx = x0-1
  uint4 cur[4], nxt[4];
  #pragma unroll
  for (int k=0;k<4;++k) {
    const int i = k*256 + tid;
    cur[k] = z4;
    if (i < 792) {
      const int row = i/264, rem = i%264;
      const int pxl = rem>>2, q = rem&3;
      const int gy = y + row - 1, gx = x0 - 1 + pxl;
      if (gy>=0 && gy<HH && gx>=0 && gx<WW)
        cur[k] = *(const uint4*)(src + (size_t)(gy*WW+gx)*128 + q*8);
    }
  }

  #pragma unroll
  for (int cb = 0; cb < 4; ++cb) {
    __syncthreads();
    #pragma unroll
    for (int k=0;k<4;++k) {
      const int i = k*256 + tid;
      if (i < 792) {
        const int row = i/264, rem = i%264;
        const int pxl = rem>>2, q = rem&3;
        *(uint4*)&lds[row*RSTR2 + pxl*CSTR + q*8] = cur[k];
      }
    }
    __syncthreads();
    if (cb < 3) {
      #pragma unroll
      for (int k=0;k<4;++k) {
        const int i = k*256 + tid;
        nxt[k] = z4;
        if (i < 792) {
          const int row = i/264, rem = i%264;
          const int pxl = rem>>2, q = rem&3;
          const int gy = y + row - 1, gx = x0 - 1 + pxl;
          if (gy>=0 && gy<HH && gx>=0 && gx<WW)
            nxt[k] = *(const uint4*)(src + (size_t)(gy*WW+gx)*128 + (cb+1)*32 + q*8);
        }
      }
    }
    #pragma unroll
    for (int tap = 0; tap < 9; ++tap) {
      const int trow = tap/3, kx = tap%3;
      const short8 af = *(const short8*)(wbf2
          + (size_t)(cw + l15)*1152 + tap*128 + cb*32 + qd*8);
      const int bbase = trow*RSTR2 + (l15 + kx)*CSTR + qd*8;
      #pragma unroll
      for (int g = 0; g < 4; ++g) {
        const short8 bfr = *(const short8*)&lds[bbase + g*16*CSTR];
        acc[g] = __builtin_amdgcn_mfma_f32_16x16x32_bf16(af, bfr, acc[g], 0, 0, 0);
      }
    }
    #pragma unroll
    for (int k=0;k<4;++k) cur[k] = nxt[k];
  }
  #pragma unroll
  for (int r = 0; r < 4; ++r) {
    const int c = cw + qd*4 + r;
    const int gg = c / 24, rr = c % 24;
    bf16* outp = (rr < 8) ? (qbuf + (size_t)(gg*8 + rr)*NPIX)
                          : (kvbuf + (size_t)(gg*16 + (rr-8))*NPIX);
    const float bias = biasc[c];
    #pragma unroll
    for (int g = 0; g < 4; ++g)
      outp[y*WW + x0 + g*16 + l15] = f2b(acc[g][r] + bias);
  }
}

// ---- merged att stage: br0 = qkv KV-reduce, br1 = ms k/v, br2 = msq --------
#define KVSTR 520
#define ATT_SMEM_BYTES 20160
__global__ __launch_bounds__(256) void k_att_ms(
    const bf16* __restrict__ kvbuf, const bf16* __restrict__ qbuf,
    const float* __restrict__ adw, const float* __restrict__ apw,
    float* __restrict__ part, bf16* __restrict__ msq)
{
  __shared__ __align__(16) unsigned char smem[ATT_SMEM_BYTES];
  const int br = blockIdx.x % 3;
  const int sub = blockIdx.x / 3;
  const int tid = threadIdx.x;
  const int lane = tid & 63;
  const int w = tid >> 6;
  const int qd = lane >> 4, l15 = lane & 15;

  if (br == 0) {
    // ---- qkv KV-reduce via MFMA (g0=0) ----
    const int s = sub & 31;
    const int gl = sub >> 5;
    const bf16* bp = kvbuf + (size_t)gl*16*NPIX;
    float (*redm)[9][8] = (float(*)[9][8])smem;
    const int k0 = s*512 + w*128 + qd*8;
    const bf16* ap = bp + (size_t)(8 + (l15 & 7))*NPIX + k0;
    const bf16* bk = bp + (size_t)(l15 & 7)*NPIX + k0;
    const short8 ones8 = {0x3F80,0x3F80,0x3F80,0x3F80,0x3F80,0x3F80,0x3F80,0x3F80};
    f32x4 mac = (f32x4){0.f,0.f,0.f,0.f};
    #pragma unroll
    for (int m = 0; m < 4; ++m) {
      short8 av = *(const short8*)(ap + m*32);
      if (l15 == 8) av = ones8;
      uint4 bu = *(const uint4*)(bk + m*32);
      bu.x = relu2(bu.x); bu.y = relu2(bu.y);
      bu.z = relu2(bu.z); bu.w = relu2(bu.w);
      const short8 bv = __builtin_bit_cast(short8, bu);
      mac = __builtin_amdgcn_mfma_f32_16x16x32_bf16(av, bv, mac, 0, 0, 0);
    }
    #pragma unroll
    for (int r = 0; r < 4; ++r) {
      const int row = qd*4 + r;
      if (l15 < 8 && row < 9) redm[w][row][l15] = mac[r];
    }
    __syncthreads();
    if (tid < 72)
      part[((size_t)gl*32 + s)*72 + tid] =
          redm[0][tid>>3][tid&7] + redm[1][tid>>3][tid&7]
        + redm[2][tid>>3][tid&7] + redm[3][tid>>3][tid&7];

  } else if (br == 1) {
    // ---- ms k/v: two-phase dw5x5 + pw8x8 + relu + MFMA KV-reduce ----
    const int t  = sub & 31;
    const int jj = sub >> 5;
    unsigned short (*sIn)[1056] = (unsigned short(*)[1056])smem;
    float (*dww)[25] = (float(*)[25])(smem + 16896);
    float (*pww)[8]  = (float(*)[8])(smem + 18496);
    float (*redm)[9][8] = (float(*)[9][8])(smem + 19008);
    unsigned short* kvA = (unsigned short*)smem;      // aliases sIn after barrier
    unsigned short* kvB = kvA + 9*KVSTR;

    for (int i = tid; i < 400; i += 256) {
      const int ch = i/25, kk5 = i%25;
      dww[ch][kk5] = adw[(24*jj + 8 + ch)*25 + kk5];
    }
    for (int i = tid; i < 128; i += 256) {
      const int r = i>>3, ii = i&7;
      pww[r][ii] = apw[(24*jj + 8 + r)*8 + ii];
    }
    if (tid < 64) {                    // zero x-pads (persist across phases)
      const int ch = tid & 7, r = tid >> 3;
      *(unsigned int*)&sIn[ch][r*132 + 0] = 0u;
      *(unsigned int*)&sIn[ch][r*132 + 130] = 0u;
    }
    const int y0 = t*4 - 2;
    const int xp = (tid & 63)*2;       // 2 output px per thread
    const int row = tid >> 6;          // output row in tile (0..3)
    float ko[8][2], mv[8][2];

    // ---- phase A: k-source channels (rows jj*16+0..7) ----
    #pragma unroll
    for (int rep = 0; rep < 4; ++rep) {
      const int L = rep*256 + tid;
      const int col8 = L & 15;
      const int rowc = L >> 4;
      const int r = rowc >> 3, ch = rowc & 7;
      const int gy = y0 + r;
      uint4 pk = make_uint4(0u,0u,0u,0u);
      if (gy >= 0 && gy < HH)
        pk = *(const uint4*)(kvbuf + (size_t)(jj*16 + ch)*NPIX + gy*WW + col8*8);
      unsigned short* dst = &sIn[ch][r*132 + 2 + col8*8];
      *(unsigned int*)(dst + 0) = pk.x;
      *(unsigned int*)(dst + 2) = pk.y;
      *(unsigned int*)(dst + 4) = pk.z;
      *(unsigned int*)(dst + 6) = pk.w;
    }
    __syncthreads();
    #pragma unroll
    for (int e=0;e<8;++e){ ko[e][0]=0.f; ko[e][1]=0.f; }
    #pragma unroll
    for (int c=0;c<8;++c) {
      float o0=0.f, o1=0.f;
      #pragma unroll
      for (int rr=0; rr<5; ++rr) {
        const unsigned int* rp = (const unsigned int*)&sIn[c][(row+rr)*132 + xp];
        float v0,v1,v2,v3,v4,v5;
        bf2x(rp[0], v0, v1); bf2x(rp[1], v2, v3); bf2x(rp[2], v4, v5);
        const float* wr = &dww[c][rr*5];
        o0 += wr[0]*v0; o0 += wr[1]*v1; o0 += wr[2]*v2; o0 += wr[3]*v3; o0 += wr[4]*v4;
        o1 += wr[0]*v1; o1 += wr[1]*v2; o1 += wr[2]*v3; o1 += wr[3]*v4; o1 += wr[4]*v5;
      }
      #pragma unroll
      for (int e=0;e<8;++e){ ko[e][0] += pww[e][c]*o0; ko[e][1] += pww[e][c]*o1; }
    }
    #pragma unroll
    for (int e=0;e<8;++e){ ko[e][0]=fmaxf(ko[e][0],0.f); ko[e][1]=fmaxf(ko[e][1],0.f); }
    __syncthreads();

    // ---- phase B: v-source channels (rows jj*16+8..15) ----
    #pragma unroll
    for (int rep = 0; rep < 4; ++rep) {
      const int L = rep*256 + tid;
      const int col8 = L & 15;
      const int rowc = L >> 4;
      const int r = rowc >> 3, ch = rowc & 7;
      const int gy = y0 + r;
      uint4 pk = make_uint4(0u,0u,0u,0u);
      if (gy >= 0 && gy < HH)
        pk = *(const uint4*)(kvbuf + (size_t)(jj*16 + 8 + ch)*NPIX + gy*WW + col8*8);
      unsigned short* dst = &sIn[ch][r*132 + 2 + col8*8];
      *(unsigned int*)(dst + 0) = pk.x;
      *(unsigned int*)(dst + 2) = pk.y;
      *(unsigned int*)(dst + 4) = pk.z;
      *(unsigned int*)(dst + 6) = pk.w;
    }
    __syncthreads();
    {
      float dv[8][2];
      #pragma unroll
      for (int c=0;c<8;++c) {
        float o0=0.f, o1=0.f;
        #pragma unroll
        for (int rr=0; rr<5; ++rr) {
          const unsigned int* rp = (const unsigned int*)&sIn[c][(row+rr)*132 + xp];
          float v0,v1,v2,v3,v4,v5;
          bf2x(rp[0], v0, v1); bf2x(rp[1], v2, v3); bf2x(rp[2], v4, v5);
          const float* wr = &dww[8+c][rr*5];
          o0 += wr[0]*v0; o0 += wr[1]*v1; o0 += wr[2]*v2; o0 += wr[3]*v3; o0 += wr[4]*v4;
          o1 += wr[0]*v1; o1 += wr[1]*v2; o1 += wr[2]*v3; o1 += wr[3]*v4; o1 += wr[4]*v5;
        }
        dv[c][0]=o0; dv[c][1]=o1;
      }
      #pragma unroll
      for (int d=0;d<8;++d) {
        float v0=0.f, v1=0.f;
        #pragma unroll
        for (int i=0;i<8;++i){ v0 += pww[8+d][i]*dv[i][0]; v1 += pww[8+d][i]*dv[i][1]; }
        mv[d][0]=v0; mv[d][1]=v1;
      }
    }
    __syncthreads();   // all reads of sIn/dww done before aliasing kvA/kvB

    const int px = row*128 + xp;       // even -> aligned u32 writes
    #pragma unroll
    for (int e=0;e<8;++e)
      *(unsigned int*)&kvB[e*KVSTR + px] =
          ((unsigned int)f2bu(ko[e][1]) << 16) | f2bu(ko[e][0]);
    #pragma unroll
    for (int d=0;d<8;++d)
      *(unsigned int*)&kvA[d*KVSTR + px] =
          ((unsigned int)f2bu(mv[d][1]) << 16) | f2bu(mv[d][0]);
    *(unsigned int*)&kvA[8*KVSTR + px] = 0x3F803F80u;   // ones row -> ksum
    __syncthreads();

    const int ra = (l15 < 9) ? l15 : 0;    // clamp junk lanes in-bounds
    const int rb = l15 & 7;
    f32x4 mac = (f32x4){0.f,0.f,0.f,0.f};
    #pragma unroll
    for (int m = 0; m < 4; ++m) {
      const int kk = w*128 + m*32 + qd*8;
      const short8 av = *(const short8*)&kvA[ra*KVSTR + kk];
      const short8 bv = *(const short8*)&kvB[rb*KVSTR + kk];
      mac = __builtin_amdgcn_mfma_f32_16x16x32_bf16(av, bv, mac, 0, 0, 0);
    }
    #pragma unroll
    for (int r = 0; r < 4; ++r) {
      const int rw = qd*4 + r;
      if (l15 < 8 && rw < 9) redm[w][rw][l15] = mac[r];
    }
    __syncthreads();
    if (tid < 72)
      part[((size_t)(16+jj)*32 + t)*72 + tid] =
          redm[0][tid>>3][tid&7] + redm[1][tid>>3][tid&7]
        + redm[2][tid>>3][tid&7] + redm[3][tid>>3][tid&7];

  } else {
    // ---- ms q: dw5x5 + pw8x8 (px-pair reads) ----
    const int t  = sub & 31;
    const int jj = sub >> 5;
    unsigned short (*sIn)[1056] = (unsigned short(*)[1056])smem;
    float (*dww)[25] = (float(*)[25])(smem + 16896);
    float (*pww)[8]  = (float(*)[8])(smem + 17696);

    for (int i = tid; i < 200; i += 256)
      dww[i/25][i%25] = adw[(24*jj + i/25)*25 + (i%25)];
    if (tid < 64)
      pww[tid>>3][tid&7] = apw[(24*jj + (tid>>3))*8 + (tid&7)];
    if (tid < 64) {
      const int ch = tid & 7, r = tid >> 3;
      *(unsigned int*)&sIn[ch][r*132 + 0] = 0u;
      *(unsigned int*)&sIn[ch][r*132 + 130] = 0u;
    }
    const int y0 = t*4 - 2;
    #pragma unroll
    for (int rep = 0; rep < 4; ++rep) {
      const int L = rep*256 + tid;
      const int col8 = L & 15;
      const int rowc = L >> 4;
      const int r = rowc >> 3, ch = rowc & 7;
      const int gy = y0 + r;
      uint4 pk = make_uint4(0u,0u,0u,0u);
      if (gy >= 0 && gy < HH)
        pk = *(const uint4*)(qbuf + (size_t)(jj*8 + ch)*NPIX + gy*WW + col8*8);
      unsigned short* dst = &sIn[ch][r*132 + 2 + col8*8];
      *(unsigned int*)(dst + 0) = pk.x;
      *(unsigned int*)(dst + 2) = pk.y;
      *(unsigned int*)(dst + 4) = pk.z;
      *(unsigned int*)(dst + 6) = pk.w;
    }
    __syncthreads();

    const int xp = (tid & 63)*2;
    const int row = tid >> 6;
    const int row0 = t*4 + row;

    float dq[8][2];
    #pragma unroll
    for (int c=0;c<8;++c) {
      float o0=0.f, o1=0.f;
      #pragma unroll
      for (int rr=0; rr<5; ++rr) {
        const unsigned int* rp = (const unsigned int*)&sIn[c][(row+rr)*132 + xp];
        float v0,v1,v2,v3,v4,v5;
        bf2x(rp[0], v0, v1); bf2x(rp[1], v2, v3); bf2x(rp[2], v4, v5);
        const float* wr = &dww[c][rr*5];
        o0 += wr[0]*v0; o0 += wr[1]*v1; o0 += wr[2]*v2; o0 += wr[3]*v3; o0 += wr[4]*v4;
        o1 += wr[0]*v1; o1 += wr[1]*v2; o1 += wr[2]*v3; o1 += wr[3]*v4; o1 += wr[4]*v5;
      }
      dq[c][0]=o0; dq[c][1]=o1;
    }
    #pragma unroll
    for (int e=0;e<8;++e) {
      float o0=0.f, o1=0.f;
      #pragma unroll
      for (int i=0;i<8;++i){ o0 += pww[e][i]*dq[i][0]; o1 += pww[e][i]*dq[i][1]; }
      *(unsigned int*)(msq + (size_t)(jj*8 + e)*NPIX + row0*WW + xp) =
          ((unsigned int)f2bu(o1) << 16) | f2bu(o0);
    }
  }
}

// ---- fold proj weights: absorbs split-sum + writes kv denominators ---------
__global__ __launch_bounds__(256) void k_fold2(
    const float* __restrict__ pjw, const float* __restrict__ part,
    const float* __restrict__ g1, const float* __restrict__ bb1,
    const float* __restrict__ m1, const float* __restrict__ v1,
    bf16* __restrict__ wtb, float* __restrict__ bias2, float* __restrict__ kvf)
{
  const int co = blockIdx.x;
  const int ge = (int)threadIdx.x;
  const int g = ge >> 3, e = ge & 7;
  float kv[8];
  #pragma unroll
  for (int d=0;d<8;++d) kv[d] = 0.f;
  for (int s = 0; s < 32; ++s) {
    const float* pp = part + ((size_t)g*32 + s)*72;
    #pragma unroll
    for (int d=0;d<8;++d) kv[d] += pp[d*8 + e];
  }
  const float sc = g1[co] * rsqrtf(v1[co] + 1e-5f);
  float acc = 0.f;
  #pragma unroll
  for (int d = 0; d < 8; ++d)
    acc += pjw[co*256 + g*8 + d] * kv[d];
  wtb[(size_t)co*256 + ge] = f2b(sc * acc);
  if (ge == 0) bias2[co] = bb1[co] - m1[co]*sc;
  if (co < 32 && ge < 8) {
    float s8 = 0.f;
    for (int s = 0; s < 32; ++s) s8 += part[((size_t)co*32 + s)*72 + 64 + ge];
    kvf[(size_t)co*72 + 64 + ge] = s8;
  }
}

// ---- MFMA att+proj ---------------------------------------------------------
__global__ __launch_bounds__(256) void k_proj_m(
    const bf16* __restrict__ qbuf, const bf16* __restrict__ msq,
    const float* __restrict__ kvf, const bf16* __restrict__ wtb,
    const float* __restrict__ bias2, const float* __restrict__ refB,
    float* __restrict__ attd)
{
  const int n0 = blockIdx.x * 64;
  __shared__ unsigned short lds[64*CSTR];
  __shared__ float kvden[32][8];
  __shared__ float b2s[128];
  const int tid = threadIdx.x;
  kvden[tid>>3][tid&7] = kvf[(size_t)(tid>>3)*72 + 64 + (tid&7)];
  if (tid < 128) b2s[tid] = bias2[tid];
  const int lane = tid & 63;
  const int w = tid >> 6;
  const int qd = lane >> 4, l15 = lane & 15;
  const int px = tid & 63;

  f32x4 acc[2][4];
  #pragma unroll
  for (int t=0;t<2;++t)
    #pragma unroll
    for (int g=0;g<4;++g) acc[t][g] = (f32x4){0.f,0.f,0.f,0.f};

  for (int cb = 0; cb < 8; ++cb) {
    __syncthreads();
    const int g = cb*4 + w;
    const bf16* base = (g < 16) ? qbuf + (size_t)g*8*NPIX
                                : msq + (size_t)(g-16)*8*NPIX;
    float q8[8];
    #pragma unroll
    for (int e=0;e<8;++e) q8[e] = fmaxf(b2f(base[(size_t)e*NPIX + n0 + px]), 0.f);
    float den = 1e-15f;
    #pragma unroll
    for (int e=0;e<8;++e) den += kvden[g][e]*q8[e];
    const float inv = 1.0f/den;
    uint4 pk;
    pk.x = ((unsigned int)f2bu(q8[1]*inv) << 16) | f2bu(q8[0]*inv);
    pk.y = ((unsigned int)f2bu(q8[3]*inv) << 16) | f2bu(q8[2]*inv);
    pk.z = ((unsigned int)f2bu(q8[5]*inv) << 16) | f2bu(q8[4]*inv);
    pk.w = ((unsigned int)f2bu(q8[7]*inv) << 16) | f2bu(q8[6]*inv);
    *(uint4*)&lds[px*CSTR + w*8] = pk;
    __syncthreads();
    const short8 af0 = *(const short8*)(wtb + (size_t)(w*32 + l15)*256 + cb*32 + qd*8);
    const short8 af1 = *(const short8*)(wtb + (size_t)(w*32 + 16 + l15)*256 + cb*32 + qd*8);
    #pragma unroll
    for (int gg = 0; gg < 4; ++gg) {
      const short8 bfr = *(const short8*)&lds[(gg*16 + l15)*CSTR + qd*8];
      acc[0][gg] = __builtin_amdgcn_mfma_f32_16x16x32_bf16(af0, bfr, acc[0][gg], 0, 0, 0);
      acc[1][gg] = __builtin_amdgcn_mfma_f32_16x16x32_bf16(af1, bfr, acc[1][gg], 0, 0, 0);
    }
  }
  #pragma unroll
  for (int t = 0; t < 2; ++t) {
    #pragma unroll
    for (int r = 0; r < 4; ++r) {
      const int co = w*32 + t*16 + qd*4 + r;
      const float bi = b2s[co];
      #pragma unroll
      for (int gg = 0; gg < 4; ++gg) {
        const int pxg = n0 + gg*16 + l15;
        attd[(size_t)co*NPIX + pxg] = refB[(size_t)co*NPIX + pxg] + acc[t][gg][r] + bi;
      }
    }
  }
}

// ---- MFMA 1x1 mb1 ----------------------------------------------------------
__global__ __launch_bounds__(256) void k_mb1_m(
    const float* __restrict__ attd, const bf16* __restrict__ w1b,
    const float* __restrict__ bias, bf16* __restrict__ h1s, int s)
{
  const int pxt = blockIdx.x & 127;
  const int cot = blockIdx.x >> 7;
  const int n0 = pxt*128;
  __shared__ unsigned short lds[128*CSTR];
  const int tid = threadIdx.x;
  const int lane = tid & 63;
  const int wv4 = tid >> 6;
  const int co16 = s*192 + cot*64 + wv4*16;
  const int qd = lane >> 4, l15 = lane & 15;
  f32x4 acc[8];
  #pragma unroll
  for (int g=0; g<8; ++g) acc[g] = (f32x4){0.f,0.f,0.f,0.f};
  const int sx = tid & 127, sp = tid >> 7;
  for (int cb = 0; cb < 4; ++cb) {
    __syncthreads();
    const float* rp = attd + (size_t)(cb*32)*NPIX + n0 + sx;
    for (int cp = sp; cp < 16; cp += 2) {
      const float a0 = rp[(size_t)(2*cp)*NPIX];
      const float a1 = rp[(size_t)(2*cp+1)*NPIX];
      *(unsigned int*)&lds[sx*CSTR + 2*cp] =
          ((unsigned int)f2bu(a1) << 16) | f2bu(a0);
    }
    __syncthreads();
    const short8 af = *(const short8*)(w1b + (size_t)(co16 + l15)*128 + cb*32 + qd*8);
    #pragma unroll
    for (int g = 0; g < 8; ++g) {
      const short8 bfr = *(const short8*)&lds[(g*16 + l15)*CSTR + qd*8];
      acc[g] = __builtin_amdgcn_mfma_f32_16x16x32_bf16(af, bfr, acc[g], 0, 0, 0);
    }
  }
  #pragma unroll
  for (int r = 0; r < 4; ++r) {
    const int co = co16 + qd*4 + r;
    const float bi = bias[co];
    bf16* op = h1s + (size_t)(co - s*192)*NPIX + n0;
    #pragma unroll
    for (int g = 0; g < 8; ++g)
      op[g*16 + l15] = f2b(hswish(acc[g][r] + bi));
  }
}

// ---- LDS-tiled 3x3 depthwise mb2 + hswish ----------------------------------
__global__ __launch_bounds__(256) void k_mb2(
    const bf16* __restrict__ h1s, const float* __restrict__ w,
    const float* __restrict__ bias, bf16* __restrict__ h2s, int s)
{
  const int rt = blockIdx.x & 3;
  const int cl = blockIdx.x >> 2;          // 0..191
  const int cg = s*192 + cl;
  __shared__ unsigned short tile[34][132];
  __shared__ float wc9[9];
  __shared__ float bsh[1];
  const int tid = threadIdx.x;
  if (tid < 9) wc9[tid] = w[cg*9 + tid];
  if (tid == 9) bsh[0] = bias[cg];
  if (tid < 136) {
    const int r = tid >> 2;
    const int csel = tid & 3;
    const int c = (csel == 0) ? 0 : (csel == 1) ? 1 : (csel == 2) ? 130 : 131;
    tile[r][c] = 0;
  }
  const int y0 = rt*32;
  const bf16* in = h1s + (size_t)cl*NPIX;
  for (int i = tid; i < 544; i += 256) {     // 34 rows * 16 uint4
    const int rr = i >> 4, c8 = i & 15;
    const int gy = y0 - 1 + rr;
    uint4 pk = make_uint4(0u,0u,0u,0u);
    if (gy >= 0 && gy < HH) pk = *(const uint4*)(in + gy*WW + c8*8);
    unsigned short* dst = &tile[rr][2 + c8*8];
    *(unsigned int*)(dst+0)=pk.x; *(unsigned int*)(dst+2)=pk.y;
    *(unsigned int*)(dst+4)=pk.z; *(unsigned int*)(dst+6)=pk.w;
  }
  __syncthreads();
  const int x = tid & 127;
  const int rb = (tid >> 7) * 16;
  float a0,b0,c0,a1,b1,c1,a2,b2,c2;
  {
    const unsigned short* p = &tile[rb][x+1];
    a0=u16f(p[0]); b0=u16f(p[1]); c0=u16f(p[2]);
    p = &tile[rb+1][x+1];
    a1=u16f(p[0]); b1=u16f(p[1]); c1=u16f(p[2]);
  }
  bf16* op = h2s + (size_t)cl*NPIX + (y0+rb)*WW + x;
  #pragma unroll
  for (int j = 0; j < 16; ++j) {
    const unsigned short* p = &tile[rb+j+2][x+1];
    a2=u16f(p[0]); b2=u16f(p[1]); c2=u16f(p[2]);
    float acc = bsh[0] + wc9[0]*a0 + wc9[1]*b0 + wc9[2]*c0
                       + wc9[3]*a1 + wc9[4]*b1 + wc9[5]*c1
                       + wc9[6]*a2 + wc9[7]*b2 + wc9[8]*c2;
    op[j*WW] = f2b(hswish(acc));
    a0=a1; b0=b1; c0=c1; a1=a2; b1=b2; c1=c2;
  }
}

// ---- merged mb3(s3 in 0..2) + mb1(s1) --------------------------------------
__global__ __launch_bounds__(256) void k_mb31(
    const bf16* __restrict__ h2s, const bf16* __restrict__ w3b,
    float* __restrict__ accb, int s3,
    const float* __restrict__ attd, const bf16* __restrict__ w1b,
    const float* __restrict__ bias1, bf16* __restrict__ h1s, int s1)
{
  __shared__ unsigned short lds[128*CSTR];
  const int tid = threadIdx.x;
  const int lane = tid & 63;
  const int wv4 = tid >> 6;
  const int qd = lane >> 4, l15 = lane & 15;
  const int sx = tid & 127, sp = tid >> 7;

  if (blockIdx.x < 256) {
    // ---- mb3 partial ----
    const int pxt = blockIdx.x & 127;
    const int cot = blockIdx.x >> 7;
    const int n0 = pxt*128;
    const int co16 = cot*64 + wv4*16;
    f32x4 acc[8];
    #pragma unroll
    for (int g=0; g<8; ++g) acc[g] = (f32x4){0.f,0.f,0.f,0.f};
    for (int cb = 0; cb < 6; ++cb) {
      __syncthreads();
      const bf16* rp = h2s + (size_t)(cb*32)*NPIX + n0 + sx;
      for (int cp = sp; cp < 16; cp += 2) {
        const unsigned short a0 = bbits(rp[(size_t)(2*cp)*NPIX]);
        const unsigned short a1 = bbits(rp[(size_t)(2*cp+1)*NPIX]);
        *(unsigned int*)&lds[sx*CSTR + 2*cp] = ((unsigned int)a1 << 16) | a0;
      }
      __syncthreads();
      const short8 af = *(const short8*)(w3b + (size_t)(co16 + l15)*768 + s3*192 + cb*32 + qd*8);
      #pragma unroll
      for (int g = 0; g < 8; ++g) {
        const short8 bfr = *(const short8*)&lds[(g*16 + l15)*CSTR + qd*8];
        acc[g] = __builtin_amdgcn_mfma_f32_16x16x32_bf16(af, bfr, acc[g], 0, 0, 0);
      }
    }
    #pragma unroll
    for (int r = 0; r < 4; ++r) {
      const int co = co16 + qd*4 + r;
      float* op = accb + (size_t)co*NPIX + n0;
      if (s3 == 0) {
        #pragma unroll
        for (int g = 0; g < 8; ++g) op[g*16 + l15] = acc[g][r];
      } else {
        #pragma unroll
        for (int g = 0; g < 8; ++g) op[g*16 + l15] += acc[g][r];
      }
    }
  } else {
    // ---- mb1 for slab s1 ----
    const int bid = blockIdx.x - 256;
    const int pxt = bid & 127;
    const int cot = bid >> 7;            // 0..2
    const int n0 = pxt*128;
    const int co16 = s1*192 + cot*64 + wv4*16;
    f32x4 acc[8];
    #pragma unroll
    for (int g=0; g<8; ++g) acc[g] = (f32x4){0.f,0.f,0.f,0.f};
    for (int cb = 0; cb < 4; ++cb) {
      __syncthreads();
      const float* rp = attd + (size_t)(cb*32)*NPIX + n0 + sx;
      for (int cp = sp; cp < 16; cp += 2) {
        const float a0 = rp[(size_t)(2*cp)*NPIX];
        const float a1 = rp[(size_t)(2*cp+1)*NPIX];
        *(unsigned int*)&lds[sx*CSTR + 2*cp] =
            ((unsigned int)f2bu(a1) << 16) | f2bu(a0);
      }
      __syncthreads();
      const short8 af = *(const short8*)(w1b + (size_t)(co16 + l15)*128 + cb*32 + qd*8);
      #pragma unroll
      for (int g = 0; g < 8; ++g) {
        const short8 bfr = *(const short8*)&lds[(g*16 + l15)*CSTR + qd*8];
        acc[g] = __builtin_amdgcn_mfma_f32_16x16x32_bf16(af, bfr, acc[g], 0, 0, 0);
      }
    }
    #pragma unroll
    for (int r = 0; r < 4; ++r) {
      const int co = co16 + qd*4 + r;
      const float bi = bias1[co];
      bf16* op = h1s + (size_t)(co - s1*192)*NPIX + n0;
      #pragma unroll
      for (int g = 0; g < 8; ++g)
        op[g*16 + l15] = f2b(hswish(acc[g][r] + bi));
    }
  }
}

// ---- final mb3 (s=3) + BN2 + residual into attd ----------------------------
__global__ __launch_bounds__(256) void k_mb3f(
    const bf16* __restrict__ h2s, const bf16* __restrict__ w3b,
    const float* __restrict__ accb,
    const float* __restrict__ g2, const float* __restrict__ b2p,
    const float* __restrict__ m2, const float* __restrict__ v2,
    float* __restrict__ attd)
{
  const int pxt = blockIdx.x & 127;
  const int cot = blockIdx.x >> 7;
  const int n0 = pxt*128;
  __shared__ unsigned short lds[128*CSTR];
  const int tid = threadIdx.x;
  const int lane = tid & 63;
  const int wv4 = tid >> 6;
  const int co16 = cot*64 + wv4*16;
  const int qd = lane >> 4, l15 = lane & 15;
  f32x4 acc[8];
  #pragma unroll
  for (int g=0; g<8; ++g) acc[g] = (f32x4){0.f,0.f,0.f,0.f};
  const int sx = tid & 127, sp = tid >> 7;
  for (int cb = 0; cb < 6; ++cb) {
    __syncthreads();
    const bf16* rp = h2s + (size_t)(cb*32)*NPIX + n0 + sx;
    for (int cp = sp; cp < 16; cp += 2) {
      const unsigned short a0 = bbits(rp[(size_t)(2*cp)*NPIX]);
      const unsigned short a1 = bbits(rp[(size_t)(2*cp+1)*NPIX]);
      *(unsigned int*)&lds[sx*CSTR + 2*cp] = ((unsigned int)a1 << 16) | a0;
    }
    __syncthreads();
    const short8 af = *(const short8*)(w3b + (size_t)(co16 + l15)*768 + 576 + cb*32 + qd*8);
    #pragma unroll
    for (int g = 0; g < 8; ++g) {
      const short8 bfr = *(const short8*)&lds[(g*16 + l15)*CSTR + qd*8];
      acc[g] = __builtin_amdgcn_mfma_f32_16x16x32_bf16(af, bfr, acc[g], 0, 0, 0);
    }
  }
  #pragma unroll
  for (int r = 0; r < 4; ++r) {
    const int co = co16 + qd*4 + r;
    const float scale = g2[co] * rsqrtf(v2[co] + 1e-5f);
    const float bb = b2p[co];
    const float mm = m2[co];
    #pragma unroll
    for (int g = 0; g < 8; ++g) {
      const size_t idx = (size_t)co*NPIX + n0 + g*16 + l15;
      const float val = accb[idx] + acc[g][r];
      const float y = (val - mm)*scale + bb;
      attd[idx] = attd[idx] + y;
    }
  }
}

extern "C" void kernel_launch(void* const* d_in, const int* in_sizes, int n_in,
                              void* d_out, int out_size, void* d_ws, size_t ws_size,
                              hipStream_t stream)
{
  const float* ref = (const float*)d_in[0];
  const float* oth = (const float*)d_in[1];
  const float* wq  = (const float*)d_in[2];
  const float* bq  = (const float*)d_in[3];
  const float* wk  = (const float*)d_in[4];
  const float* bk  = (const float*)d_in[5];
  const float* wv  = (const float*)d_in[6];
  const float* bv  = (const float*)d_in[7];
  const float* adw = (const float*)d_in[8];
  const float* apw = (const float*)d_in[9];
  const float* pjw = (const float*)d_in[10];
  const float* g1  = (const float*)d_in[11];
  const float* b1  = (const float*)d_in[12];
  const float* m1  = (const float*)d_in[13];
  const float* v1  = (const float*)d_in[14];
  const float* w1  = (const float*)d_in[15];
  const float* bb1 = (const float*)d_in[16];
  const float* w2  = (const float*)d_in[17];
  const float* bb2 = (const float*)d_in[18];
  const float* w3  = (const float*)d_in[19];
  const float* g2  = (const float*)d_in[20];
  const float* b2p = (const float*)d_in[21];
  const float* m2  = (const float*)d_in[22];
  const float* v2  = (const float*)d_in[23];

  char* ws = (char*)d_ws;
  bf16*  wbf2  = (bf16*)(ws + 0);
  float* biasc = (float*)(ws + 884736);
  bf16*  w1b   = (bf16*)(ws + 886272);
  bf16*  w3b   = (bf16*)(ws + 1082880);
  bf16*  kvbuf = (bf16*)(ws + 1279488);
  bf16*  qbuf  = (bf16*)(ws + 9668096);
  bf16*  nh    = (bf16*)(ws + 13862400);
  bf16*  msq   = (bf16*)(ws + 13862400);
  float* part  = (float*)(ws + 22251008);
  float* kvf   = (float*)(ws + 22545920);
  bf16*  wtb   = (bf16*)(ws + 22555136);
  float* bias2 = (float*)(ws + 22620672);
  float* accb  = (float*)(ws + 1279488);
  bf16*  h1s   = (bf16*)(ws + 9668096);
  bf16*  h2s   = (bf16*)(ws + 15959552);

  k_wprep<<<1728, 256, 0, stream>>>(wq, wk, wv, bq, bk, bv, w1, w3, wbf2, biasc, w1b, w3b);

  for (int b = 0; b < 4; ++b) {
    const float* refB = ref + (size_t)b*128*NPIX;
    const float* othB = oth + (size_t)b*128*NPIX;
    float* attd = (float*)d_out + (size_t)b*128*NPIX;

    k_nhwc   <<<256,  256, 0, stream>>>(refB, othB, nh);
    k_conv   <<<1536, 256, 0, stream>>>(nh, wbf2, biasc, kvbuf, qbuf);
    k_att_ms <<<1536, 256, 0, stream>>>(kvbuf, qbuf, adw, apw, part, msq);
    k_fold2  <<<128,  256, 0, stream>>>(pjw, part, g1, b1, m1, v1, wtb, bias2, kvf);
    k_proj_m <<<256,  256, 0, stream>>>(qbuf, msq, kvf, wtb, bias2, refB, attd);

    k_mb1_m  <<<384,  256, 0, stream>>>(attd, w1b, bb1, h1s, 0);
    k_mb2    <<<768,  256, 0, stream>>>(h1s, w2, bb2, h2s, 0);
    for (int s = 0; s < 3; ++s) {
      k_mb31 <<<640,  256, 0, stream>>>(h2s, w3b, accb, s, attd, w1b, bb1, h1s, s+1);
      k_mb2  <<<768,  256, 0, stream>>>(h1s, w2, bb2, h2s, s+1);
    }
    k_mb3f   <<<256,  256, 0, stream>>>(h2s, w3b, accb, g2, b2p, m2, v2, attd);
  }
}

// Round 12
// 760.645 us; speedup vs baseline: 1.1153x; 1.0645x over previous
//
#include <hip/hip_runtime.h>
#include <hip/hip_bf16.h>

#define HH 128
#define WW 128
#define NPIX 16384

using bf16 = __hip_bfloat16;
typedef __attribute__((ext_vector_type(8))) short short8;
typedef __attribute__((ext_vector_type(4))) float f32x4;

__device__ __forceinline__ float b2f(bf16 x){ return __bfloat162float(x); }
__device__ __forceinline__ bf16 f2b(float x){ return __float2bfloat16(x); }
__device__ __forceinline__ unsigned short f2bu(float x){
  bf16 h = __float2bfloat16(x);
  return __builtin_bit_cast(unsigned short, h);
}
__device__ __forceinline__ unsigned short bbits(bf16 x){
  return __builtin_bit_cast(unsigned short, x);
}
__device__ __forceinline__ float u16f(unsigned short u){
  return __bfloat162float(__builtin_bit_cast(bf16, u));
}
__device__ __forceinline__ void bf2x(unsigned int u, float& a, float& b){
  a = u16f((unsigned short)(u & 0xffffu));
  b = u16f((unsigned short)(u >> 16));
}
__device__ __forceinline__ unsigned int relu2(unsigned int x){
  unsigned int s = x & 0x80008000u;
  unsigned int t = s >> 15;
  unsigned int m = (t << 16) - t;
  return x & ~m;
}
__device__ __forceinline__ float hswish(float x){
  float t = fminf(fmaxf(x + 3.0f, 0.0f), 6.0f);
  return x * t * (1.0f/6.0f);
}

// ---- weight prep -----------------------------------------------------------
__global__ __launch_bounds__(256) void k_wprep(
    const float* __restrict__ wq, const float* __restrict__ wk,
    const float* __restrict__ wv, const float* __restrict__ bq,
    const float* __restrict__ bk, const float* __restrict__ bv,
    const float* __restrict__ w1, const float* __restrict__ w3,
    bf16* __restrict__ wbf2, float* __restrict__ biasc,
    bf16* __restrict__ w1b, bf16* __restrict__ w3b)
{
  const int idx = blockIdx.x*256 + (int)threadIdx.x;
  if (idx < 384)
    biasc[idx] = (idx < 128) ? bq[idx] : (idx < 256 ? bk[idx-128] : bv[idx-256]);
  if (idx < 98304) {
    w1b[idx] = f2b(w1[idx]);
    w3b[idx] = f2b(w3[idx]);
  }
  if (idx < 384*1152) {
    const int c = idx / 1152, rem = idx % 1152;
    const int tap = rem >> 7, ci = rem & 127;
    const float* wsrc = (c < 128) ? wq : (c < 256 ? wk : wv);
    const int cl = (c < 128) ? c : (c < 256 ? c-128 : c-256);
    wbf2[idx] = f2b(wsrc[(size_t)cl*1152 + ci*9 + tap]);
  }
}

// ---- NCHW fp32 -> NHWC bf16 ------------------------------------------------
__global__ __launch_bounds__(256) void k_nhwc(
    const float* __restrict__ refB, const float* __restrict__ othB,
    bf16* __restrict__ nh)
{
  const int pt = blockIdx.x & 127;
  const int sidx = blockIdx.x >> 7;
  const float* src = sidx ? othB : refB;
  __shared__ unsigned short t[128][130];
  const int tid = threadIdx.x;
  const int px4 = (tid & 31) * 4;
  const int cq = tid >> 5;
  #pragma unroll
  for (int cb = 0; cb < 16; ++cb) {
    const int c = cb*8 + cq;
    const float4 f = *(const float4*)(src + (size_t)c*NPIX + pt*128 + px4);
    t[px4+0][c] = f2bu(f.x); t[px4+1][c] = f2bu(f.y);
    t[px4+2][c] = f2bu(f.z); t[px4+3][c] = f2bu(f.w);
  }
  __syncthreads();
  bf16* op = nh + (size_t)sidx*NPIX*128 + (size_t)pt*128*128;
  #pragma unroll
  for (int i = tid; i < 2048; i += 256) {
    const int p = i >> 4;
    const int k = i & 15;
    const unsigned short* tp = &t[p][k*8];
    uint4 v;
    v.x = ((unsigned)tp[1]<<16)|tp[0];
    v.y = ((unsigned)tp[3]<<16)|tp[2];
    v.z = ((unsigned)tp[5]<<16)|tp[4];
    v.w = ((unsigned)tp[7]<<16)|tp[6];
    *(uint4*)(op + (size_t)p*128 + k*8) = v;
  }
}

// ---- MFMA implicit-GEMM 3x3 conv (R9 verified version) ---------------------
#define CSTR 40
#define RSTR 5200   // 130*40
__global__ __launch_bounds__(256) void k_conv(
    const bf16* __restrict__ nh, const bf16* __restrict__ wbf2,
    const float* __restrict__ biasc,
    bf16* __restrict__ kvbuf, bf16* __restrict__ qbuf)
{
  const int y = blockIdx.x & 127;
  const int tile = blockIdx.x >> 7;
  const bf16* src = nh + (size_t)((tile < 2) ? 0 : 1)*NPIX*128;
  const int c0 = (tile < 2) ? tile*64 : 128 + (tile-2)*64;
  __shared__ unsigned short lds[3*RSTR];
  const int tid = threadIdx.x;
  const int lane = tid & 63;
  const int wv4 = tid >> 6;
  const int cw = c0 + wv4*16;
  const int qd = lane >> 4;
  const int l15 = lane & 15;

  f32x4 acc[8];
  #pragma unroll
  for (int g=0; g<8; ++g) acc[g] = (f32x4){0.f,0.f,0.f,0.f};

  if (tid < 192) {
    const int row = tid / 64;
    const int col = ((tid >> 5) & 1) ? 129 : 0;
    const int ci = tid & 31;
    lds[(row*130 + col)*CSTR + ci] = 0;
  }

  const int sx = tid & 127;
  const int sp = tid >> 7;
  const int ldsw = (sx + 1)*CSTR + sp*16;
  const uint4 z4 = make_uint4(0u,0u,0u,0u);

  uint4 cur[3][2], nxt[3][2];
  #pragma unroll
  for (int row = 0; row < 3; ++row) {
    const int yy = y + row - 1;
    if (yy >= 0 && yy < HH) {
      const bf16* p = src + (size_t)(yy*WW + sx)*128 + sp*16;
      cur[row][0] = *(const uint4*)(p);
      cur[row][1] = *(const uint4*)(p + 8);
    } else { cur[row][0] = z4; cur[row][1] = z4; }
  }

  #pragma unroll
  for (int cb = 0; cb < 4; ++cb) {
    __syncthreads();
    #pragma unroll
    for (int row = 0; row < 3; ++row) {
      *(uint4*)&lds[row*RSTR + ldsw]     = cur[row][0];
      *(uint4*)&lds[row*RSTR + ldsw + 8] = cur[row][1];
    }
    __syncthreads();
    if (cb < 3) {
      #pragma unroll
      for (int row = 0; row < 3; ++row) {
        const int yy = y + row - 1;
        if (yy >= 0 && yy < HH) {
          const bf16* p = src + (size_t)(yy*WW + sx)*128 + (cb+1)*32 + sp*16;
          nxt[row][0] = *(const uint4*)(p);
          nxt[row][1] = *(const uint4*)(p + 8);
        } else { nxt[row][0] = z4; nxt[row][1] = z4; }
      }
    }
    #pragma unroll
    for (int tap = 0; tap < 9; ++tap) {
      const int trow = tap/3, kx = tap%3;
      const short8 af = *(const short8*)(wbf2
          + (size_t)(cw + l15)*1152 + tap*128 + cb*32 + qd*8);
      const int bbase = trow*RSTR + (l15 + kx)*CSTR + qd*8;
      #pragma unroll
      for (int g = 0; g < 8; ++g) {
        const short8 bfr = *(const short8*)&lds[bbase + g*16*CSTR];
        acc[g] = __builtin_amdgcn_mfma_f32_16x16x32_bf16(af, bfr, acc[g], 0, 0, 0);
      }
    }
    #pragma unroll
    for (int row = 0; row < 3; ++row) {
      cur[row][0] = nxt[row][0];
      cur[row][1] = nxt[row][1];
    }
  }
  #pragma unroll
  for (int r = 0; r < 4; ++r) {
    const int c = cw + qd*4 + r;
    const int gg = c / 24, rr = c % 24;
    bf16* outp = (rr < 8) ? (qbuf + (size_t)(gg*8 + rr)*NPIX)
                          : (kvbuf + (size_t)(gg*16 + (rr-8))*NPIX);
    const float bias = biasc[c];
    #pragma unroll
    for (int g = 0; g < 8; ++g)
      outp[y*WW + g*16 + l15] = f2b(acc[g][r] + bias);
  }
}

// ---- merged att stage: br0 = qkv KV-reduce, br1 = ms k/v, br2 = msq --------
#define KVSTR 520
#define ATT_SMEM_BYTES 20160
__global__ __launch_bounds__(256) void k_att_ms(
    const bf16* __restrict__ kvbuf, const bf16* __restrict__ qbuf,
    const float* __restrict__ adw, const float* __restrict__ apw,
    float* __restrict__ part, bf16* __restrict__ msq)
{
  __shared__ __align__(16) unsigned char smem[ATT_SMEM_BYTES];
  const int br = blockIdx.x % 3;
  const int sub = blockIdx.x / 3;
  const int tid = threadIdx.x;
  const int lane = tid & 63;
  const int w = tid >> 6;
  const int qd = lane >> 4, l15 = lane & 15;

  if (br == 0) {
    // ---- qkv KV-reduce via MFMA (g0=0) ----
    const int s = sub & 31;
    const int gl = sub >> 5;
    const bf16* bp = kvbuf + (size_t)gl*16*NPIX;
    float (*redm)[9][8] = (float(*)[9][8])smem;
    const int k0 = s*512 + w*128 + qd*8;
    const bf16* ap = bp + (size_t)(8 + (l15 & 7))*NPIX + k0;
    const bf16* bk = bp + (size_t)(l15 & 7)*NPIX + k0;
    const short8 ones8 = {0x3F80,0x3F80,0x3F80,0x3F80,0x3F80,0x3F80,0x3F80,0x3F80};
    f32x4 mac = (f32x4){0.f,0.f,0.f,0.f};
    #pragma unroll
    for (int m = 0; m < 4; ++m) {
      short8 av = *(const short8*)(ap + m*32);
      if (l15 == 8) av = ones8;
      uint4 bu = *(const uint4*)(bk + m*32);
      bu.x = relu2(bu.x); bu.y = relu2(bu.y);
      bu.z = relu2(bu.z); bu.w = relu2(bu.w);
      const short8 bv = __builtin_bit_cast(short8, bu);
      mac = __builtin_amdgcn_mfma_f32_16x16x32_bf16(av, bv, mac, 0, 0, 0);
    }
    #pragma unroll
    for (int r = 0; r < 4; ++r) {
      const int row = qd*4 + r;
      if (l15 < 8 && row < 9) redm[w][row][l15] = mac[r];
    }
    __syncthreads();
    if (tid < 72)
      part[((size_t)gl*32 + s)*72 + tid] =
          redm[0][tid>>3][tid&7] + redm[1][tid>>3][tid&7]
        + redm[2][tid>>3][tid&7] + redm[3][tid>>3][tid&7];

  } else if (br == 1) {
    // ---- ms k/v: two-phase dw5x5 + pw8x8 + relu + MFMA KV-reduce ----
    const int t  = sub & 31;
    const int jj = sub >> 5;
    unsigned short (*sIn)[1056] = (unsigned short(*)[1056])smem;
    float (*dww)[25] = (float(*)[25])(smem + 16896);
    float (*pww)[8]  = (float(*)[8])(smem + 18496);
    float (*redm)[9][8] = (float(*)[9][8])(smem + 19008);
    unsigned short* kvA = (unsigned short*)smem;      // aliases sIn after barrier
    unsigned short* kvB = kvA + 9*KVSTR;

    for (int i = tid; i < 400; i += 256) {
      const int ch = i/25, kk5 = i%25;
      dww[ch][kk5] = adw[(24*jj + 8 + ch)*25 + kk5];
    }
    for (int i = tid; i < 128; i += 256) {
      const int r = i>>3, ii = i&7;
      pww[r][ii] = apw[(24*jj + 8 + r)*8 + ii];
    }
    if (tid < 64) {                    // zero x-pads (persist across phases)
      const int ch = tid & 7, r = tid >> 3;
      *(unsigned int*)&sIn[ch][r*132 + 0] = 0u;
      *(unsigned int*)&sIn[ch][r*132 + 130] = 0u;
    }
    const int y0 = t*4 - 2;
    const int xp = (tid & 63)*2;       // 2 output px per thread
    const int row = tid >> 6;          // output row in tile (0..3)
    float ko[8][2], mv[8][2];

    // ---- phase A: k-source channels (rows jj*16+0..7) ----
    #pragma unroll
    for (int rep = 0; rep < 4; ++rep) {
      const int L = rep*256 + tid;
      const int col8 = L & 15;
      const int rowc = L >> 4;
      const int r = rowc >> 3, ch = rowc & 7;
      const int gy = y0 + r;
      uint4 pk = make_uint4(0u,0u,0u,0u);
      if (gy >= 0 && gy < HH)
        pk = *(const uint4*)(kvbuf + (size_t)(jj*16 + ch)*NPIX + gy*WW + col8*8);
      unsigned short* dst = &sIn[ch][r*132 + 2 + col8*8];
      *(unsigned int*)(dst + 0) = pk.x;
      *(unsigned int*)(dst + 2) = pk.y;
      *(unsigned int*)(dst + 4) = pk.z;
      *(unsigned int*)(dst + 6) = pk.w;
    }
    __syncthreads();
    #pragma unroll
    for (int e=0;e<8;++e){ ko[e][0]=0.f; ko[e][1]=0.f; }
    #pragma unroll
    for (int c=0;c<8;++c) {
      float o0=0.f, o1=0.f;
      #pragma unroll
      for (int rr=0; rr<5; ++rr) {
        const unsigned int* rp = (const unsigned int*)&sIn[c][(row+rr)*132 + xp];
        float v0,v1,v2,v3,v4,v5;
        bf2x(rp[0], v0, v1); bf2x(rp[1], v2, v3); bf2x(rp[2], v4, v5);
        const float* wr = &dww[c][rr*5];
        o0 += wr[0]*v0; o0 += wr[1]*v1; o0 += wr[2]*v2; o0 += wr[3]*v3; o0 += wr[4]*v4;
        o1 += wr[0]*v1; o1 += wr[1]*v2; o1 += wr[2]*v3; o1 += wr[3]*v4; o1 += wr[4]*v5;
      }
      #pragma unroll
      for (int e=0;e<8;++e){ ko[e][0] += pww[e][c]*o0; ko[e][1] += pww[e][c]*o1; }
    }
    #pragma unroll
    for (int e=0;e<8;++e){ ko[e][0]=fmaxf(ko[e][0],0.f); ko[e][1]=fmaxf(ko[e][1],0.f); }
    __syncthreads();

    // ---- phase B: v-source channels (rows jj*16+8..15) ----
    #pragma unroll
    for (int rep = 0; rep < 4; ++rep) {
      const int L = rep*256 + tid;
      const int col8 = L & 15;
      const int rowc = L >> 4;
      const int r = rowc >> 3, ch = rowc & 7;
      const int gy = y0 + r;
      uint4 pk = make_uint4(0u,0u,0u,0u);
      if (gy >= 0 && gy < HH)
        pk = *(const uint4*)(kvbuf + (size_t)(jj*16 + 8 + ch)*NPIX + gy*WW + col8*8);
      unsigned short* dst = &sIn[ch][r*132 + 2 + col8*8];
      *(unsigned int*)(dst + 0) = pk.x;
      *(unsigned int*)(dst + 2) = pk.y;
      *(unsigned int*)(dst + 4) = pk.z;
      *(unsigned int*)(dst + 6) = pk.w;
    }
    __syncthreads();
    {
      float dv[8][2];
      #pragma unroll
      for (int c=0;c<8;++c) {
        float o0=0.f, o1=0.f;
        #pragma unroll
        for (int rr=0; rr<5; ++rr) {
          const unsigned int* rp = (const unsigned int*)&sIn[c][(row+rr)*132 + xp];
          float v0,v1,v2,v3,v4,v5;
          bf2x(rp[0], v0, v1); bf2x(rp[1], v2, v3); bf2x(rp[2], v4, v5);
          const float* wr = &dww[8+c][rr*5];
          o0 += wr[0]*v0; o0 += wr[1]*v1; o0 += wr[2]*v2; o0 += wr[3]*v3; o0 += wr[4]*v4;
          o1 += wr[0]*v1; o1 += wr[1]*v2; o1 += wr[2]*v3; o1 += wr[3]*v4; o1 += wr[4]*v5;
        }
        dv[c][0]=o0; dv[c][1]=o1;
      }
      #pragma unroll
      for (int d=0;d<8;++d) {
        float v0=0.f, v1=0.f;
        #pragma unroll
        for (int i=0;i<8;++i){ v0 += pww[8+d][i]*dv[i][0]; v1 += pww[8+d][i]*dv[i][1]; }
        mv[d][0]=v0; mv[d][1]=v1;
      }
    }
    __syncthreads();   // all reads of sIn/dww done before aliasing kvA/kvB

    const int px = row*128 + xp;       // even -> aligned u32 writes
    #pragma unroll
    for (int e=0;e<8;++e)
      *(unsigned int*)&kvB[e*KVSTR + px] =
          ((unsigned int)f2bu(ko[e][1]) << 16) | f2bu(ko[e][0]);
    #pragma unroll
    for (int d=0;d<8;++d)
      *(unsigned int*)&kvA[d*KVSTR + px] =
          ((unsigned int)f2bu(mv[d][1]) << 16) | f2bu(mv[d][0]);
    *(unsigned int*)&kvA[8*KVSTR + px] = 0x3F803F80u;   // ones row -> ksum
    __syncthreads();

    const int ra = (l15 < 9) ? l15 : 0;    // clamp junk lanes in-bounds
    const int rb = l15 & 7;
    f32x4 mac = (f32x4){0.f,0.f,0.f,0.f};
    #pragma unroll
    for (int m = 0; m < 4; ++m) {
      const int kk = w*128 + m*32 + qd*8;
      const short8 av = *(const short8*)&kvA[ra*KVSTR + kk];
      const short8 bv = *(const short8*)&kvB[rb*KVSTR + kk];
      mac = __builtin_amdgcn_mfma_f32_16x16x32_bf16(av, bv, mac, 0, 0, 0);
    }
    #pragma unroll
    for (int r = 0; r < 4; ++r) {
      const int rw = qd*4 + r;
      if (l15 < 8 && rw < 9) redm[w][rw][l15] = mac[r];
    }
    __syncthreads();
    if (tid < 72)
      part[((size_t)(16+jj)*32 + t)*72 + tid] =
          redm[0][tid>>3][tid&7] + redm[1][tid>>3][tid&7]
        + redm[2][tid>>3][tid&7] + redm[3][tid>>3][tid&7];

  } else {
    // ---- ms q: dw5x5 + pw8x8 (px-pair reads) ----
    const int t  = sub & 31;
    const int jj = sub >> 5;
    unsigned short (*sIn)[1056] = (unsigned short(*)[1056])smem;
    float (*dww)[25] = (float(*)[25])(smem + 16896);
    float (*pww)[8]  = (float(*)[8])(smem + 17696);

    for (int i = tid; i < 200; i += 256)
      dww[i/25][i%25] = adw[(24*jj + i/25)*25 + (i%25)];
    if (tid < 64)
      pww[tid>>3][tid&7] = apw[(24*jj + (tid>>3))*8 + (tid&7)];
    if (tid < 64) {
      const int ch = tid & 7, r = tid >> 3;
      *(unsigned int*)&sIn[ch][r*132 + 0] = 0u;
      *(unsigned int*)&sIn[ch][r*132 + 130] = 0u;
    }
    const int y0 = t*4 - 2;
    #pragma unroll
    for (int rep = 0; rep < 4; ++rep) {
      const int L = rep*256 + tid;
      const int col8 = L & 15;
      const int rowc = L >> 4;
      const int r = rowc >> 3, ch = rowc & 7;
      const int gy = y0 + r;
      uint4 pk = make_uint4(0u,0u,0u,0u);
      if (gy >= 0 && gy < HH)
        pk = *(const uint4*)(qbuf + (size_t)(jj*8 + ch)*NPIX + gy*WW + col8*8);
      unsigned short* dst = &sIn[ch][r*132 + 2 + col8*8];
      *(unsigned int*)(dst + 0) = pk.x;
      *(unsigned int*)(dst + 2) = pk.y;
      *(unsigned int*)(dst + 4) = pk.z;
      *(unsigned int*)(dst + 6) = pk.w;
    }
    __syncthreads();

    const int xp = (tid & 63)*2;
    const int row = tid >> 6;
    const int row0 = t*4 + row;

    float dq[8][2];
    #pragma unroll
    for (int c=0;c<8;++c) {
      float o0=0.f, o1=0.f;
      #pragma unroll
      for (int rr=0; rr<5; ++rr) {
        const unsigned int* rp = (const unsigned int*)&sIn[c][(row+rr)*132 + xp];
        float v0,v1,v2,v3,v4,v5;
        bf2x(rp[0], v0, v1); bf2x(rp[1], v2, v3); bf2x(rp[2], v4, v5);
        const float* wr = &dww[c][rr*5];
        o0 += wr[0]*v0; o0 += wr[1]*v1; o0 += wr[2]*v2; o0 += wr[3]*v3; o0 += wr[4]*v4;
        o1 += wr[0]*v1; o1 += wr[1]*v2; o1 += wr[2]*v3; o1 += wr[3]*v4; o1 += wr[4]*v5;
      }
      dq[c][0]=o0; dq[c][1]=o1;
    }
    #pragma unroll
    for (int e=0;e<8;++e) {
      float o0=0.f, o1=0.f;
      #pragma unroll
      for (int i=0;i<8;++i){ o0 += pww[e][i]*dq[i][0]; o1 += pww[e][i]*dq[i][1]; }
      *(unsigned int*)(msq + (size_t)(jj*8 + e)*NPIX + row0*WW + xp) =
          ((unsigned int)f2bu(o1) << 16) | f2bu(o0);
    }
  }
}

// ---- fold proj weights: absorbs split-sum + writes kv denominators ---------
__global__ __launch_bounds__(256) void k_fold2(
    const float* __restrict__ pjw, const float* __restrict__ part,
    const float* __restrict__ g1, const float* __restrict__ bb1,
    const float* __restrict__ m1, const float* __restrict__ v1,
    bf16* __restrict__ wtb, float* __restrict__ bias2, float* __restrict__ kvf)
{
  const int co = blockIdx.x;
  const int ge = (int)threadIdx.x;
  const int g = ge >> 3, e = ge & 7;
  float kv[8];
  #pragma unroll
  for (int d=0;d<8;++d) kv[d] = 0.f;
  for (int s = 0; s < 32; ++s) {
    const float* pp = part + ((size_t)g*32 + s)*72;
    #pragma unroll
    for (int d=0;d<8;++d) kv[d] += pp[d*8 + e];
  }
  const float sc = g1[co] * rsqrtf(v1[co] + 1e-5f);
  float acc = 0.f;
  #pragma unroll
  for (int d = 0; d < 8; ++d)
    acc += pjw[co*256 + g*8 + d] * kv[d];
  wtb[(size_t)co*256 + ge] = f2b(sc * acc);
  if (ge == 0) bias2[co] = bb1[co] - m1[co]*sc;
  if (co < 32 && ge < 8) {
    float s8 = 0.f;
    for (int s = 0; s < 32; ++s) s8 += part[((size_t)co*32 + s)*72 + 64 + ge];
    kvf[(size_t)co*72 + 64 + ge] = s8;
  }
}

// ---- MFMA att+proj ---------------------------------------------------------
__global__ __launch_bounds__(256) void k_proj_m(
    const bf16* __restrict__ qbuf, const bf16* __restrict__ msq,
    const float* __restrict__ kvf, const bf16* __restrict__ wtb,
    const float* __restrict__ bias2, const float* __restrict__ refB,
    float* __restrict__ attd)
{
  const int n0 = blockIdx.x * 64;
  __shared__ unsigned short lds[64*CSTR];
  __shared__ float kvden[32][8];
  __shared__ float b2s[128];
  const int tid = threadIdx.x;
  kvden[tid>>3][tid&7] = kvf[(size_t)(tid>>3)*72 + 64 + (tid&7)];
  if (tid < 128) b2s[tid] = bias2[tid];
  const int lane = tid & 63;
  const int w = tid >> 6;
  const int qd = lane >> 4, l15 = lane & 15;
  const int px = tid & 63;

  f32x4 acc[2][4];
  #pragma unroll
  for (int t=0;t<2;++t)
    #pragma unroll
    for (int g=0;g<4;++g) acc[t][g] = (f32x4){0.f,0.f,0.f,0.f};

  for (int cb = 0; cb < 8; ++cb) {
    __syncthreads();
    const int g = cb*4 + w;
    const bf16* base = (g < 16) ? qbuf + (size_t)g*8*NPIX
                                : msq + (size_t)(g-16)*8*NPIX;
    float q8[8];
    #pragma unroll
    for (int e=0;e<8;++e) q8[e] = fmaxf(b2f(base[(size_t)e*NPIX + n0 + px]), 0.f);
    float den = 1e-15f;
    #pragma unroll
    for (int e=0;e<8;++e) den += kvden[g][e]*q8[e];
    const float inv = 1.0f/den;
    uint4 pk;
    pk.x = ((unsigned int)f2bu(q8[1]*inv) << 16) | f2bu(q8[0]*inv);
    pk.y = ((unsigned int)f2bu(q8[3]*inv) << 16) | f2bu(q8[2]*inv);
    pk.z = ((unsigned int)f2bu(q8[5]*inv) << 16) | f2bu(q8[4]*inv);
    pk.w = ((unsigned int)f2bu(q8[7]*inv) << 16) | f2bu(q8[6]*inv);
    *(uint4*)&lds[px*CSTR + w*8] = pk;
    __syncthreads();
    const short8 af0 = *(const short8*)(wtb + (size_t)(w*32 + l15)*256 + cb*32 + qd*8);
    const short8 af1 = *(const short8*)(wtb + (size_t)(w*32 + 16 + l15)*256 + cb*32 + qd*8);
    #pragma unroll
    for (int gg = 0; gg < 4; ++gg) {
      const short8 bfr = *(const short8*)&lds[(gg*16 + l15)*CSTR + qd*8];
      acc[0][gg] = __builtin_amdgcn_mfma_f32_16x16x32_bf16(af0, bfr, acc[0][gg], 0, 0, 0);
      acc[1][gg] = __builtin_amdgcn_mfma_f32_16x16x32_bf16(af1, bfr, acc[1][gg], 0, 0, 0);
    }
  }
  #pragma unroll
  for (int t = 0; t < 2; ++t) {
    #pragma unroll
    for (int r = 0; r < 4; ++r) {
      const int co = w*32 + t*16 + qd*4 + r;
      const float bi = b2s[co];
      #pragma unroll
      for (int gg = 0; gg < 4; ++gg) {
        const int pxg = n0 + gg*16 + l15;
        attd[(size_t)co*NPIX + pxg] = refB[(size_t)co*NPIX + pxg] + acc[t][gg][r] + bi;
      }
    }
  }
}

// ---- MFMA 1x1 mb1 ----------------------------------------------------------
__global__ __launch_bounds__(256) void k_mb1_m(
    const float* __restrict__ attd, const bf16* __restrict__ w1b,
    const float* __restrict__ bias, bf16* __restrict__ h1s, int s)
{
  const int pxt = blockIdx.x & 127;
  const int cot = blockIdx.x >> 7;
  const int n0 = pxt*128;
  __shared__ unsigned short lds[128*CSTR];
  const int tid = threadIdx.x;
  const int lane = tid & 63;
  const int wv4 = tid >> 6;
  const int co16 = s*192 + cot*64 + wv4*16;
  const int qd = lane >> 4, l15 = lane & 15;
  f32x4 acc[8];
  #pragma unroll
  for (int g=0; g<8; ++g) acc[g] = (f32x4){0.f,0.f,0.f,0.f};
  const int sx = tid & 127, sp = tid >> 7;
  for (int cb = 0; cb < 4; ++cb) {
    __syncthreads();
    const float* rp = attd + (size_t)(cb*32)*NPIX + n0 + sx;
    for (int cp = sp; cp < 16; cp += 2) {
      const float a0 = rp[(size_t)(2*cp)*NPIX];
      const float a1 = rp[(size_t)(2*cp+1)*NPIX];
      *(unsigned int*)&lds[sx*CSTR + 2*cp] =
          ((unsigned int)f2bu(a1) << 16) | f2bu(a0);
    }
    __syncthreads();
    const short8 af = *(const short8*)(w1b + (size_t)(co16 + l15)*128 + cb*32 + qd*8);
    #pragma unroll
    for (int g = 0; g < 8; ++g) {
      const short8 bfr = *(const short8*)&lds[(g*16 + l15)*CSTR + qd*8];
      acc[g] = __builtin_amdgcn_mfma_f32_16x16x32_bf16(af, bfr, acc[g], 0, 0, 0);
    }
  }
  #pragma unroll
  for (int r = 0; r < 4; ++r) {
    const int co = co16 + qd*4 + r;
    const float bi = bias[co];
    bf16* op = h1s + (size_t)(co - s*192)*NPIX + n0;
    #pragma unroll
    for (int g = 0; g < 8; ++g)
      op[g*16 + l15] = f2b(hswish(acc[g][r] + bi));
  }
}

// ---- LDS-tiled 3x3 depthwise mb2 + hswish ----------------------------------
// grid: 1536 = 192 ch * 8 rowtiles(16); data at tile col 2 (aligned u32 writes)
__global__ __launch_bounds__(256) void k_mb2(
    const bf16* __restrict__ h1s, const float* __restrict__ w,
    const float* __restrict__ bias, bf16* __restrict__ h2s, int s)
{
  const int rt = blockIdx.x & 7;
  const int cl = blockIdx.x >> 3;          // 0..191
  const int cg = s*192 + cl;
  __shared__ unsigned short tile[18][132];
  __shared__ float wc9[9];
  __shared__ float bsh[1];
  const int tid = threadIdx.x;
  if (tid < 9) wc9[tid] = w[cg*9 + tid];
  if (tid == 9) bsh[0] = bias[cg];
  if (tid < 36) {
    const int r = tid >> 1;
    const int c = (tid & 1) ? 130 : 0;
    *(unsigned int*)&tile[r][c] = 0u;      // zeros cols {0,1} or {130,131}
  }
  const int y0 = rt*16;
  const bf16* in = h1s + (size_t)cl*NPIX;
  for (int i = tid; i < 288; i += 256) {   // 18 rows * 16 uint4
    const int rr = i >> 4, c8 = i & 15;
    const int gy = y0 - 1 + rr;
    uint4 pk = make_uint4(0u,0u,0u,0u);
    if (gy >= 0 && gy < HH) pk = *(const uint4*)(in + gy*WW + c8*8);
    unsigned short* dst = &tile[rr][2 + c8*8];
    *(unsigned int*)(dst+0)=pk.x; *(unsigned int*)(dst+2)=pk.y;
    *(unsigned int*)(dst+4)=pk.z; *(unsigned int*)(dst+6)=pk.w;
  }
  __syncthreads();
  const int x = tid & 127;
  const int rb = (tid >> 7) * 8;
  float a0,b0,c0,a1,b1,c1,a2,b2,c2;
  {
    const unsigned short* p = &tile[rb][x+1];
    a0=u16f(p[0]); b0=u16f(p[1]); c0=u16f(p[2]);
    p = &tile[rb+1][x+1];
    a1=u16f(p[0]); b1=u16f(p[1]); c1=u16f(p[2]);
  }
  bf16* op = h2s + (size_t)cl*NPIX + (y0+rb)*WW + x;
  #pragma unroll
  for (int j = 0; j < 8; ++j) {
    const unsigned short* p = &tile[rb+j+2][x+1];
    a2=u16f(p[0]); b2=u16f(p[1]); c2=u16f(p[2]);
    float acc = bsh[0] + wc9[0]*a0 + wc9[1]*b0 + wc9[2]*c0
                       + wc9[3]*a1 + wc9[4]*b1 + wc9[5]*c1
                       + wc9[6]*a2 + wc9[7]*b2 + wc9[8]*c2;
    op[j*WW] = f2b(hswish(acc));
    a0=a1; b0=b1; c0=c1; a1=a2; b1=b2; c1=c2;
  }
}

// ---- merged mb3(s3 in 0..2) + mb1(s1) --------------------------------------
__global__ __launch_bounds__(256) void k_mb31(
    const bf16* __restrict__ h2s, const bf16* __restrict__ w3b,
    float* __restrict__ accb, int s3,
    const float* __restrict__ attd, const bf16* __restrict__ w1b,
    const float* __restrict__ bias1, bf16* __restrict__ h1s, int s1)
{
  __shared__ unsigned short lds[128*CSTR];
  const int tid = threadIdx.x;
  const int lane = tid & 63;
  const int wv4 = tid >> 6;
  const int qd = lane >> 4, l15 = lane & 15;
  const int sx = tid & 127, sp = tid >> 7;

  if (blockIdx.x < 256) {
    // ---- mb3 partial ----
    const int pxt = blockIdx.x & 127;
    const int cot = blockIdx.x >> 7;
    const int n0 = pxt*128;
    const int co16 = cot*64 + wv4*16;
    f32x4 acc[8];
    #pragma unroll
    for (int g=0; g<8; ++g) acc[g] = (f32x4){0.f,0.f,0.f,0.f};
    for (int cb = 0; cb < 6; ++cb) {
      __syncthreads();
      const bf16* rp = h2s + (size_t)(cb*32)*NPIX + n0 + sx;
      for (int cp = sp; cp < 16; cp += 2) {
        const unsigned short a0 = bbits(rp[(size_t)(2*cp)*NPIX]);
        const unsigned short a1 = bbits(rp[(size_t)(2*cp+1)*NPIX]);
        *(unsigned int*)&lds[sx*CSTR + 2*cp] = ((unsigned int)a1 << 16) | a0;
      }
      __syncthreads();
      const short8 af = *(const short8*)(w3b + (size_t)(co16 + l15)*768 + s3*192 + cb*32 + qd*8);
      #pragma unroll
      for (int g = 0; g < 8; ++g) {
        const short8 bfr = *(const short8*)&lds[(g*16 + l15)*CSTR + qd*8];
        acc[g] = __builtin_amdgcn_mfma_f32_16x16x32_bf16(af, bfr, acc[g], 0, 0, 0);
      }
    }
    #pragma unroll
    for (int r = 0; r < 4; ++r) {
      const int co = co16 + qd*4 + r;
      float* op = accb + (size_t)co*NPIX + n0;
      if (s3 == 0) {
        #pragma unroll
        for (int g = 0; g < 8; ++g) op[g*16 + l15] = acc[g][r];
      } else {
        #pragma unroll
        for (int g = 0; g < 8; ++g) op[g*16 + l15] += acc[g][r];
      }
    }
  } else {
    // ---- mb1 for slab s1 ----
    const int bid = blockIdx.x - 256;
    const int pxt = bid & 127;
    const int cot = bid >> 7;            // 0..2
    const int n0 = pxt*128;
    const int co16 = s1*192 + cot*64 + wv4*16;
    f32x4 acc[8];
    #pragma unroll
    for (int g=0; g<8; ++g) acc[g] = (f32x4){0.f,0.f,0.f,0.f};
    for (int cb = 0; cb < 4; ++cb) {
      __syncthreads();
      const float* rp = attd + (size_t)(cb*32)*NPIX + n0 + sx;
      for (int cp = sp; cp < 16; cp += 2) {
        const float a0 = rp[(size_t)(2*cp)*NPIX];
        const float a1 = rp[(size_t)(2*cp+1)*NPIX];
        *(unsigned int*)&lds[sx*CSTR + 2*cp] =
            ((unsigned int)f2bu(a1) << 16) | f2bu(a0);
      }
      __syncthreads();
      const short8 af = *(const short8*)(w1b + (size_t)(co16 + l15)*128 + cb*32 + qd*8);
      #pragma unroll
      for (int g = 0; g < 8; ++g) {
        const short8 bfr = *(const short8*)&lds[(g*16 + l15)*CSTR + qd*8];
        acc[g] = __builtin_amdgcn_mfma_f32_16x16x32_bf16(af, bfr, acc[g], 0, 0, 0);
      }
    }
    #pragma unroll
    for (int r = 0; r < 4; ++r) {
      const int co = co16 + qd*4 + r;
      const float bi = bias1[co];
      bf16* op = h1s + (size_t)(co - s1*192)*NPIX + n0;
      #pragma unroll
      for (int g = 0; g < 8; ++g)
        op[g*16 + l15] = f2b(hswish(acc[g][r] + bi));
    }
  }
}

// ---- final mb3 (s=3) + BN2 + residual into attd ----------------------------
__global__ __launch_bounds__(256) void k_mb3f(
    const bf16* __restrict__ h2s, const bf16* __restrict__ w3b,
    const float* __restrict__ accb,
    const float* __restrict__ g2, const float* __restrict__ b2p,
    const float* __restrict__ m2, const float* __restrict__ v2,
    float* __restrict__ attd)
{
  const int pxt = blockIdx.x & 127;
  const int cot = blockIdx.x >> 7;
  const int n0 = pxt*128;
  __shared__ unsigned short lds[128*CSTR];
  const int tid = threadIdx.x;
  const int lane = tid & 63;
  const int wv4 = tid >> 6;
  const int co16 = cot*64 + wv4*16;
  const int qd = lane >> 4, l15 = lane & 15;
  f32x4 acc[8];
  #pragma unroll
  for (int g=0; g<8; ++g) acc[g] = (f32x4){0.f,0.f,0.f,0.f};
  const int sx = tid & 127, sp = tid >> 7;
  for (int cb = 0; cb < 6; ++cb) {
    __syncthreads();
    const bf16* rp = h2s + (size_t)(cb*32)*NPIX + n0 + sx;
    for (int cp = sp; cp < 16; cp += 2) {
      const unsigned short a0 = bbits(rp[(size_t)(2*cp)*NPIX]);
      const unsigned short a1 = bbits(rp[(size_t)(2*cp+1)*NPIX]);
      *(unsigned int*)&lds[sx*CSTR + 2*cp] = ((unsigned int)a1 << 16) | a0;
    }
    __syncthreads();
    const short8 af = *(const short8*)(w3b + (size_t)(co16 + l15)*768 + 576 + cb*32 + qd*8);
    #pragma unroll
    for (int g = 0; g < 8; ++g) {
      const short8 bfr = *(const short8*)&lds[(g*16 + l15)*CSTR + qd*8];
      acc[g] = __builtin_amdgcn_mfma_f32_16x16x32_bf16(af, bfr, acc[g], 0, 0, 0);
    }
  }
  #pragma unroll
  for (int r = 0; r < 4; ++r) {
    const int co = co16 + qd*4 + r;
    const float scale = g2[co] * rsqrtf(v2[co] + 1e-5f);
    const float bb = b2p[co];
    const float mm = m2[co];
    #pragma unroll
    for (int g = 0; g < 8; ++g) {
      const size_t idx = (size_t)co*NPIX + n0 + g*16 + l15;
      const float val = accb[idx] + acc[g][r];
      const float y = (val - mm)*scale + bb;
      attd[idx] = attd[idx] + y;
    }
  }
}

extern "C" void kernel_launch(void* const* d_in, const int* in_sizes, int n_in,
                              void* d_out, int out_size, void* d_ws, size_t ws_size,
                              hipStream_t stream)
{
  const float* ref = (const float*)d_in[0];
  const float* oth = (const float*)d_in[1];
  const float* wq  = (const float*)d_in[2];
  const float* bq  = (const float*)d_in[3];
  const float* wk  = (const float*)d_in[4];
  const float* bk  = (const float*)d_in[5];
  const float* wv  = (const float*)d_in[6];
  const float* bv  = (const float*)d_in[7];
  const float* adw = (const float*)d_in[8];
  const float* apw = (const float*)d_in[9];
  const float* pjw = (const float*)d_in[10];
  const float* g1  = (const float*)d_in[11];
  const float* b1  = (const float*)d_in[12];
  const float* m1  = (const float*)d_in[13];
  const float* v1  = (const float*)d_in[14];
  const float* w1  = (const float*)d_in[15];
  const float* bb1 = (const float*)d_in[16];
  const float* w2  = (const float*)d_in[17];
  const float* bb2 = (const float*)d_in[18];
  const float* w3  = (const float*)d_in[19];
  const float* g2  = (const float*)d_in[20];
  const float* b2p = (const float*)d_in[21];
  const float* m2  = (const float*)d_in[22];
  const float* v2  = (const float*)d_in[23];

  char* ws = (char*)d_ws;
  bf16*  wbf2  = (bf16*)(ws + 0);
  float* biasc = (float*)(ws + 884736);
  bf16*  w1b   = (bf16*)(ws + 886272);
  bf16*  w3b   = (bf16*)(ws + 1082880);
  bf16*  kvbuf = (bf16*)(ws + 1279488);
  bf16*  qbuf  = (bf16*)(ws + 9668096);
  bf16*  nh    = (bf16*)(ws + 13862400);
  bf16*  msq   = (bf16*)(ws + 13862400);
  float* part  = (float*)(ws + 22251008);
  float* kvf   = (float*)(ws + 22545920);
  bf16*  wtb   = (bf16*)(ws + 22555136);
  float* bias2 = (float*)(ws + 22620672);
  float* accb  = (float*)(ws + 1279488);
  bf16*  h1s   = (bf16*)(ws + 9668096);
  bf16*  h2s   = (bf16*)(ws + 15959552);

  k_wprep<<<1728, 256, 0, stream>>>(wq, wk, wv, bq, bk, bv, w1, w3, wbf2, biasc, w1b, w3b);

  for (int b = 0; b < 4; ++b) {
    const float* refB = ref + (size_t)b*128*NPIX;
    const float* othB = oth + (size_t)b*128*NPIX;
    float* attd = (float*)d_out + (size_t)b*128*NPIX;

    k_nhwc   <<<256,  256, 0, stream>>>(refB, othB, nh);
    k_conv   <<<768,  256, 0, stream>>>(nh, wbf2, biasc, kvbuf, qbuf);
    k_att_ms <<<1536, 256, 0, stream>>>(kvbuf, qbuf, adw, apw, part, msq);
    k_fold2  <<<128,  256, 0, stream>>>(pjw, part, g1, b1, m1, v1, wtb, bias2, kvf);
    k_proj_m <<<256,  256, 0, stream>>>(qbuf, msq, kvf, wtb, bias2, refB, attd);

    k_mb1_m  <<<384,  256, 0, stream>>>(attd, w1b, bb1, h1s, 0);
    k_mb2    <<<1536, 256, 0, stream>>>(h1s, w2, bb2, h2s, 0);
    for (int s = 0; s < 3; ++s) {
      k_mb31 <<<640,  256, 0, stream>>>(h2s, w3b, accb, s, attd, w1b, bb1, h1s, s+1);
      k_mb2  <<<1536, 256, 0, stream>>>(h1s, w2, bb2, h2s, s+1);
    }
    k_mb3f   <<<256,  256, 0, stream>>>(h2s, w3b, accb, g2, b2p, m2, v2, attd);
  }
}